// Round 1
// baseline (591.941 us; speedup 1.0000x reference)
//
#include <hip/hip_runtime.h>
#include <hip/hip_bf16.h>
#include <math.h>

// Problem constants
#define L_    768
#define Cs_   384
#define Cz_   128
#define Ch_   16
#define H_    12
#define Pq_   4
#define Pv_   8
#define NB_   30
#define HC_   192
#define CONCAT_ 2112
#define PROJN 1152   // 192 q + 384 kv + 144 qp + 432 kvp

// scales
#define SCALE_QK  0.14433756729740643f   // sqrt(1/48)
#define SQRT3INV  0.5773502691896258f    // sqrt(1/3)
#define WC_       0.13608276348795434f   // sqrt(1/54)

// ---------------- K1: pack projection weights ----------------
__global__ void pack_kernel(const float* __restrict__ Wq, const float* __restrict__ bq,
                            const float* __restrict__ Wkv, const float* __restrict__ bkv,
                            const float* __restrict__ Wqp, const float* __restrict__ bqp,
                            const float* __restrict__ Wkvp, const float* __restrict__ bkvp,
                            float* __restrict__ Wall, float* __restrict__ ball) {
  int e = blockIdx.x * 256 + threadIdx.x;
  if (e < Cs_ * PROJN) {
    int k = e / PROJN, col = e % PROJN;
    float v;
    if (col < 192)      v = Wq[k*192 + col];
    else if (col < 576) v = Wkv[k*384 + (col-192)];
    else if (col < 720) v = Wqp[k*144 + (col-576)];
    else                v = Wkvp[k*432 + (col-720)];
    Wall[e] = v;
  } else if (e < Cs_ * PROJN + PROJN) {
    int col = e - Cs_ * PROJN;
    float v;
    if (col < 192)      v = bq[col];
    else if (col < 576) v = bkv[col-192];
    else if (col < 720) v = bqp[col-576];
    else                v = bkvp[col-720];
    ball[col] = v;
  }
}

// ---------------- generic tiled fp32 GEMM:  C = A(MxK) @ B(KxN) + bias ----------------
template<int BM, int BN, int BK, int TM, int TN>
__global__ __launch_bounds__(256) void gemm_f32(const float* __restrict__ A,
                                                const float* __restrict__ B,
                                                const float* __restrict__ bias,
                                                float* __restrict__ C,
                                                int M, int N, int K) {
  __shared__ float As[BK][BM + 1];
  __shared__ float Bs[BK][BN + 1];
  const int t = threadIdx.x;
  const int m0 = blockIdx.x * BM, n0 = blockIdx.y * BN;
  float acc[TM][TN];
  #pragma unroll
  for (int i = 0; i < TM; ++i)
    #pragma unroll
    for (int j = 0; j < TN; ++j) acc[i][j] = 0.f;

  const int tm = (t / (BN / TN)) * TM;
  const int tn = (t % (BN / TN)) * TN;

  for (int kk = 0; kk < K; kk += BK) {
    for (int e = t; e < BM * BK; e += 256) {
      int m = e / BK, k = e % BK;
      As[k][m] = A[(m0 + m) * K + kk + k];
    }
    for (int e = t; e < BK * BN; e += 256) {
      int k = e / BN, n = e % BN;
      Bs[k][n] = B[(kk + k) * N + n0 + n];
    }
    __syncthreads();
    #pragma unroll
    for (int k = 0; k < BK; ++k) {
      float av[TM], bv[TN];
      #pragma unroll
      for (int i = 0; i < TM; ++i) av[i] = As[k][tm + i];
      #pragma unroll
      for (int j = 0; j < TN; ++j) bv[j] = Bs[k][tn + j];
      #pragma unroll
      for (int i = 0; i < TM; ++i)
        #pragma unroll
        for (int j = 0; j < TN; ++j) acc[i][j] += av[i] * bv[j];
    }
    __syncthreads();
  }
  #pragma unroll
  for (int i = 0; i < TM; ++i)
    #pragma unroll
    for (int j = 0; j < TN; ++j)
      C[(m0 + tm + i) * N + n0 + tn + j] = acc[i][j] + bias[n0 + tn + j];
}

// ---------------- K3: rotate points into global frame ----------------
// q_pts:  [i][h][p(4)][3]     (i-major)
// k_pts:  [h][i][p(4)*3]      (h-major for per-head staging)
// v_pts:  [h][i][p(8)*3]
__global__ void pointize(const float* __restrict__ proj, const float* __restrict__ rot,
                         const float* __restrict__ trans,
                         float* __restrict__ qpts, float* __restrict__ kpts,
                         float* __restrict__ vpts) {
  int g = blockIdx.x * 256 + threadIdx.x;
  if (g >= L_ * 192) return;
  int i = g / 192, r = g % 192, h = r / 16, pp = r % 16;
  const float* prow = proj + i * PROJN;
  float lx, ly, lz;
  if (pp < 4) {                       // q point, flat cols 576 + d*48 + (h*4+p)
    int idx = h * 4 + pp;
    lx = prow[576 + idx]; ly = prow[576 + 48 + idx]; lz = prow[576 + 96 + idx];
  } else {                            // kv point, flat cols 720 + d*144 + (h*12+p)
    int idx = h * 12 + (pp - 4);
    lx = prow[720 + idx]; ly = prow[720 + 144 + idx]; lz = prow[720 + 288 + idx];
  }
  const float* R = rot + i * 9;
  const float* tr = trans + i * 3;
  float gx = R[0]*lx + R[1]*ly + R[2]*lz + tr[0];
  float gy = R[3]*lx + R[4]*ly + R[5]*lz + tr[1];
  float gz = R[6]*lx + R[7]*ly + R[8]*lz + tr[2];
  if (pp < 4) {
    float* q = qpts + i*144 + h*12 + pp*3;
    q[0] = gx; q[1] = gy; q[2] = gz;
  } else {
    int p = pp - 4;
    if (p < 4) { float* o = kpts + (h*L_ + i)*12 + p*3;     o[0]=gx; o[1]=gy; o[2]=gz; }
    else       { float* o = vpts + (h*L_ + i)*24 + (p-4)*3; o[0]=gx; o[1]=gy; o[2]=gz; }
  }
}

// ---------------- K4: sparse edge bias:  bias_e[i][k][h] = sqrt(1/3) * z[i,k,:]@W_b[:,h] ----------------
__global__ __launch_bounds__(256) void bias_edge_kernel(const float* __restrict__ z,
                                                        const float* __restrict__ Wb,
                                                        float* __restrict__ bias_e) {
  int i = blockIdx.x;
  __shared__ float zs[NB_ * Cz_];    // 15KB
  __shared__ float wbs[Cz_ * H_];    // 6KB
  int t = threadIdx.x;
  for (int e = t; e < NB_ * Cz_; e += 256) zs[e] = z[i * NB_ * Cz_ + e];
  for (int e = t; e < Cz_ * H_; e += 256) wbs[e] = Wb[e];
  __syncthreads();
  for (int o = t; o < NB_ * H_; o += 256) {
    int k = o / H_, h = o % H_;
    float acc = 0.f;
    #pragma unroll 8
    for (int c = 0; c < Cz_; ++c) acc += zs[k * Cz_ + c] * wbs[c * H_ + h];
    bias_e[i * NB_ * H_ + o] = SQRT3INV * acc;
  }
}

// ---------------- K5: fused attention ----------------
// block = 256 threads = 8 groups of 32 lanes; group ti handles row i0+ti.
// grid = (96 i-tiles, 12 heads)
#define TI 8
// padded LDS strides (coprime with 32 banks)
#define KCS 17
#define KPS 13
#define VCS 41
__global__ __launch_bounds__(256) void attn_kernel(
    const float* __restrict__ proj,    // [768][1152]
    const float* __restrict__ qpts,    // [768][12][12]
    const float* __restrict__ kpts,    // [12][768][12]
    const float* __restrict__ vpts,    // [12][768][24]
    const float* __restrict__ bias_e,  // [768][30][12] (pre-scaled by sqrt(1/3))
    const int*   __restrict__ E_idx,   // [768][30]
    const float* __restrict__ rot,     // [768][9]
    const float* __restrict__ trans,   // [768][3]
    const float* __restrict__ maskp,   // [768]
    const float* __restrict__ z,       // [768][30][128]
    const float* __restrict__ head_w,  // [12]
    const float* __restrict__ b_b,     // [12]
    float* __restrict__ cat)           // [768][2112]
{
  const int h = blockIdx.y;
  const int i0 = blockIdx.x * TI;
  const int t = threadIdx.x;
  const int lane = t & 31, grp = t >> 5;

  __shared__ float S[TI][L_];          // 24KB: logits then exp(P)
  __shared__ float U[256 * (VCS + 1)]; // 42KB union buffer (k/kpts/mask staging, then v/vpts staging)
  __shared__ float qs[TI][16];
  __shared__ float qps[TI][12];
  __shared__ float mrow[TI];
  __shared__ float denom_s[TI];
  __shared__ float ew[TI][NB_];
  __shared__ int   eidx[TI][NB_];
  __shared__ float opts[TI][24];

  // stage per-row q, q_pts, E_idx, mask
  for (int e = t; e < TI * 16; e += 256) { int ti = e >> 4, c = e & 15; qs[ti][c] = proj[(i0 + ti) * PROJN + h * 16 + c]; }
  for (int e = t; e < TI * 12; e += 256) { int ti = e / 12, c = e % 12; qps[ti][c] = qpts[(i0 + ti) * 144 + h * 12 + c]; }
  for (int e = t; e < TI * NB_; e += 256) { int ti = e / NB_, k = e % NB_; eidx[ti][k] = E_idx[(i0 + ti) * NB_ + k]; }
  if (t < TI) mrow[t] = maskp[i0 + t];
  const float hw = log1pf(expf(head_w[h])) * WC_;
  const float bb = SQRT3INV * b_b[h];
  __syncthreads();

  // ---- phase 1: logits ----
  const float* kbase = proj + 192 + h * 32;          // k[j][c] at kbase[j*1152 + c]
  const float* kp_h  = kpts + h * L_ * 12;
  float* kc  = U;               // [256][KCS]
  float* kpc = U + 256 * KCS;   // [256][KPS]
  float* mc  = U + 256 * (KCS + KPS);  // [256]
  for (int chnk = 0; chnk < 3; ++chnk) {
    const int j0 = chnk * 256;
    for (int e = t; e < 256 * 16; e += 256) { int jl = e >> 4, c = e & 15; kc[jl * KCS + c] = kbase[(j0 + jl) * PROJN + c]; }
    for (int e = t; e < 256 * 12; e += 256) { int jl = e / 12, c = e % 12; kpc[jl * KPS + c] = kp_h[(j0 + jl) * 12 + c]; }
    mc[t] = maskp[j0 + t];
    __syncthreads();
    #pragma unroll
    for (int jj = 0; jj < 8; ++jj) {
      const int jl = lane + jj * 32;
      float qk = 0.f;
      #pragma unroll
      for (int c = 0; c < 16; ++c) qk += qs[grp][c] * kc[jl * KCS + c];
      float ss = 0.f;
      #pragma unroll
      for (int c = 0; c < 12; ++c) { float d = qps[grp][c] - kpc[jl * KPS + c]; ss += d * d; }
      S[grp][j0 + jl] = qk * SCALE_QK - 0.5f * hw * ss + bb
                        + 100000.0f * (mrow[grp] * mc[jl] - 1.0f);
    }
    __syncthreads();
  }

  // ---- phase 2: sparse edge bias ----
  if (t < TI * NB_) {
    int ti = t / NB_, k = t % NB_;
    S[ti][eidx[ti][k]] += bias_e[(i0 + ti) * NB_ * H_ + k * H_ + h];
  }
  __syncthreads();

  // ---- phase 3: softmax (unnormalized; keep denom) ----
  {
    float m = -1e30f;
    #pragma unroll
    for (int r = 0; r < 24; ++r) m = fmaxf(m, S[grp][lane + r * 32]);
    #pragma unroll
    for (int d = 16; d; d >>= 1) m = fmaxf(m, __shfl_xor(m, d, 32));
    float sum = 0.f;
    #pragma unroll
    for (int r = 0; r < 24; ++r) {
      int j = lane + r * 32;
      float p = expf(S[grp][j] - m);
      S[grp][j] = p;
      sum += p;
    }
    #pragma unroll
    for (int d = 16; d; d >>= 1) sum += __shfl_xor(sum, d, 32);
    if (lane == 0) denom_s[grp] = sum;
  }
  __syncthreads();

  // extract edge weights for o_pair
  if (t < TI * NB_) { int ti = t / NB_, k = t % NB_; ew[ti][k] = S[ti][eidx[ti][k]]; }

  // ---- phase 4: o (16 ch) + o_pt sums (24 ch) ----
  float acc0 = 0.f, acc1 = 0.f;
  const float* vbase = proj + 192 + h * 32 + 16;
  const float* vp_h  = vpts + h * L_ * 24;
  for (int chnk = 0; chnk < 3; ++chnk) {
    const int j0 = chnk * 256;
    float* vc = U;  // [256][VCS]
    for (int e = t; e < 256 * 40; e += 256) {
      int jl = e / 40, c = e % 40;
      vc[jl * VCS + c] = (c < 16) ? vbase[(j0 + jl) * PROJN + c]
                                  : vp_h[(j0 + jl) * 24 + (c - 16)];
    }
    __syncthreads();
    #pragma unroll 4
    for (int jl = 0; jl < 256; ++jl) {
      float p = S[grp][j0 + jl];
      acc0 += p * vc[jl * VCS + lane];
      if (lane < 8) acc1 += p * vc[jl * VCS + 32 + lane];
    }
    __syncthreads();
  }
  const float dinv = 1.0f / denom_s[grp];
  {
    const int i = i0 + grp;
    if (lane < 16) cat[i * CONCAT_ + h * 16 + lane] = acc0 * dinv;   // o
    else opts[grp][lane - 16] = acc0;                                 // pt sums 0..15
    if (lane < 8) opts[grp][16 + lane] = acc1;                        // pt sums 16..23
  }
  __syncthreads();

  // ---- phase 4b: inverse-rotate o_pt, norms ----
  if (t < TI * 8) {
    int ti = t >> 3, p = t & 7;
    int i = i0 + ti;
    float di = 1.0f / denom_s[ti];
    const float* tr = trans + i * 3;
    float gx = opts[ti][p * 3 + 0] * di - tr[0];
    float gy = opts[ti][p * 3 + 1] * di - tr[1];
    float gz = opts[ti][p * 3 + 2] * di - tr[2];
    const float* R = rot + i * 9;
    float lx = R[0] * gx + R[3] * gy + R[6] * gz;   // R^T
    float ly = R[1] * gx + R[4] * gy + R[7] * gz;
    float lz = R[2] * gx + R[5] * gy + R[8] * gz;
    float nrm = sqrtf(lx * lx + ly * ly + lz * lz + 1e-8f);
    float* crow = cat + i * CONCAT_;
    crow[192 + 0 * 96 + h * 8 + p] = lx;
    crow[192 + 1 * 96 + h * 8 + p] = ly;
    crow[192 + 2 * 96 + h * 8 + p] = lz;
    crow[480 + h * 8 + p] = nrm;
  }

  // ---- phase 5: sparse o_pair ----
  {
    const int i = i0 + grp;
    const float* zrow = z + i * NB_ * Cz_;
    float a0 = 0.f, a1 = 0.f, a2 = 0.f, a3 = 0.f;
    #pragma unroll 5
    for (int k = 0; k < NB_; ++k) {
      float w = ew[grp][k];
      const float* zp = zrow + k * Cz_;
      a0 += w * zp[lane];
      a1 += w * zp[lane + 32];
      a2 += w * zp[lane + 64];
      a3 += w * zp[lane + 96];
    }
    float* crow = cat + i * CONCAT_ + 576 + h * Cz_;
    crow[lane]      = a0 * dinv;
    crow[lane + 32] = a1 * dinv;
    crow[lane + 64] = a2 * dinv;
    crow[lane + 96] = a3 * dinv;
  }
}

// ---------------- launch ----------------
extern "C" void kernel_launch(void* const* d_in, const int* in_sizes, int n_in,
                              void* d_out, int out_size, void* d_ws, size_t ws_size,
                              hipStream_t stream) {
  const float* s      = (const float*)d_in[0];
  const float* z      = (const float*)d_in[1];
  const float* rot    = (const float*)d_in[2];
  const float* trans  = (const float*)d_in[3];
  const float* mask   = (const float*)d_in[4];
  const int*   E      = (const int*)  d_in[5];
  const float* W_q    = (const float*)d_in[6];
  const float* b_q    = (const float*)d_in[7];
  const float* W_kv   = (const float*)d_in[8];
  const float* b_kv   = (const float*)d_in[9];
  const float* W_qp   = (const float*)d_in[10];
  const float* b_qp   = (const float*)d_in[11];
  const float* W_kvp  = (const float*)d_in[12];
  const float* b_kvp  = (const float*)d_in[13];
  const float* W_b    = (const float*)d_in[14];
  const float* b_b    = (const float*)d_in[15];
  const float* head_w = (const float*)d_in[16];
  const float* W_out  = (const float*)d_in[17];
  const float* b_out  = (const float*)d_in[18];

  float* ws = (float*)d_ws;
  float* Wall   = ws;                 // 442368
  float* ball   = ws + 442368;        // 1152
  float* proj   = ws + 443520;        // 884736
  float* qpts   = ws + 1328256;       // 110592
  float* kpts   = ws + 1438848;       // 110592
  float* vpts   = ws + 1549440;       // 221184
  float* bias_e = ws + 1770624;       // 276480
  float* cat    = ws + 2047104;       // 1622016   (end 3669120 floats = 14.0 MB)

  pack_kernel<<<(Cs_ * PROJN + PROJN + 255) / 256, 256, 0, stream>>>(
      W_q, b_q, W_kv, b_kv, W_qp, b_qp, W_kvp, b_kvp, Wall, ball);

  gemm_f32<64, 64, 32, 4, 4><<<dim3(L_ / 64, PROJN / 64), 256, 0, stream>>>(
      s, Wall, ball, proj, L_, PROJN, Cs_);

  pointize<<<(L_ * 192 + 255) / 256, 256, 0, stream>>>(proj, rot, trans, qpts, kpts, vpts);

  bias_edge_kernel<<<L_, 256, 0, stream>>>(z, W_b, bias_e);

  attn_kernel<<<dim3(L_ / TI, H_), 256, 0, stream>>>(
      proj, qpts, kpts, vpts, bias_e, E, rot, trans, mask, z, head_w, b_b, cat);

  gemm_f32<64, 32, 32, 4, 2><<<dim3(L_ / 64, Cs_ / 32), 256, 0, stream>>>(
      cat, W_out, b_out, (float*)d_out, L_, Cs_, CONCAT_);
}

// Round 2
// 270.509 us; speedup vs baseline: 2.1882x; 2.1882x over previous
//
#include <hip/hip_runtime.h>
#include <hip/hip_bf16.h>
#include <math.h>

// Problem constants
#define L_    768
#define Cs_   384
#define Cz_   128
#define Ch_   16
#define H_    12
#define Pq_   4
#define Pv_   8
#define NB_   30
#define HC_   192
#define CONCAT_ 2112
#define PROJN 1152   // 192 q + 384 kv + 144 qp + 432 kvp

#define SCALE_QK  0.14433756729740643f   // sqrt(1/48)
#define SQRT3INV  0.5773502691896258f    // sqrt(1/3)
#define WC_       0.13608276348795434f   // sqrt(1/54)
#define INF_      100000.0f

typedef short bf16x8 __attribute__((ext_vector_type(8)));
typedef float f32x4 __attribute__((ext_vector_type(4)));

__device__ __forceinline__ short f2b(float f) {
  __hip_bfloat16 b = __float2bfloat16(f);
  return *reinterpret_cast<short*>(&b);
}

// ---------------- K1: pack projection weights ----------------
__global__ void pack_kernel(const float* __restrict__ Wq, const float* __restrict__ bq,
                            const float* __restrict__ Wkv, const float* __restrict__ bkv,
                            const float* __restrict__ Wqp, const float* __restrict__ bqp,
                            const float* __restrict__ Wkvp, const float* __restrict__ bkvp,
                            float* __restrict__ Wall, float* __restrict__ ball) {
  int e = blockIdx.x * 256 + threadIdx.x;
  if (e < Cs_ * PROJN) {
    int k = e / PROJN, col = e % PROJN;
    float v;
    if (col < 192)      v = Wq[k*192 + col];
    else if (col < 576) v = Wkv[k*384 + (col-192)];
    else if (col < 720) v = Wqp[k*144 + (col-576)];
    else                v = Wkvp[k*432 + (col-720)];
    Wall[e] = v;
  } else if (e < Cs_ * PROJN + PROJN) {
    int col = e - Cs_ * PROJN;
    float v;
    if (col < 192)      v = bq[col];
    else if (col < 576) v = bkv[col-192];
    else if (col < 720) v = bqp[col-576];
    else                v = bkvp[col-720];
    ball[col] = v;
  }
}

// ---------------- tiled fp32 GEMM:  C = A(MxK) @ B(KxN) + bias ----------------
template<int BM, int BN, int BK, int TM, int TN>
__global__ __launch_bounds__(256) void gemm_f32(const float* __restrict__ A,
                                                const float* __restrict__ B,
                                                const float* __restrict__ bias,
                                                float* __restrict__ C,
                                                int M, int N, int K) {
  __shared__ float As[BK][BM + 1];
  __shared__ float Bs[BK][BN + 1];
  const int t = threadIdx.x;
  const int m0 = blockIdx.x * BM, n0 = blockIdx.y * BN;
  float acc[TM][TN];
  #pragma unroll
  for (int i = 0; i < TM; ++i)
    #pragma unroll
    for (int j = 0; j < TN; ++j) acc[i][j] = 0.f;

  const int tm = (t / (BN / TN)) * TM;
  const int tn = (t % (BN / TN)) * TN;

  for (int kk = 0; kk < K; kk += BK) {
    for (int e = t; e < BM * BK; e += 256) {
      int m = e / BK, k = e % BK;
      As[k][m] = A[(m0 + m) * K + kk + k];
    }
    for (int e = t; e < BK * BN; e += 256) {
      int k = e / BN, n = e % BN;
      Bs[k][n] = B[(kk + k) * N + n0 + n];
    }
    __syncthreads();
    #pragma unroll
    for (int k = 0; k < BK; ++k) {
      float av[TM], bv[TN];
      #pragma unroll
      for (int i = 0; i < TM; ++i) av[i] = As[k][tm + i];
      #pragma unroll
      for (int j = 0; j < TN; ++j) bv[j] = Bs[k][tn + j];
      #pragma unroll
      for (int i = 0; i < TM; ++i)
        #pragma unroll
        for (int j = 0; j < TN; ++j) acc[i][j] += av[i] * bv[j];
    }
    __syncthreads();
  }
  #pragma unroll
  for (int i = 0; i < TM; ++i)
    #pragma unroll
    for (int j = 0; j < TN; ++j)
      C[(m0 + tm + i) * N + n0 + tn + j] = acc[i][j] + bias[n0 + tn + j];
}

// ---------------- K3: rotate points into global frame ----------------
__global__ void pointize(const float* __restrict__ proj, const float* __restrict__ rot,
                         const float* __restrict__ trans,
                         float* __restrict__ qpts, float* __restrict__ kpts,
                         float* __restrict__ vpts) {
  int g = blockIdx.x * 256 + threadIdx.x;
  if (g >= L_ * 192) return;
  int i = g / 192, r = g % 192, h = r / 16, pp = r % 16;
  const float* prow = proj + i * PROJN;
  float lx, ly, lz;
  if (pp < 4) {
    int idx = h * 4 + pp;
    lx = prow[576 + idx]; ly = prow[576 + 48 + idx]; lz = prow[576 + 96 + idx];
  } else {
    int idx = h * 12 + (pp - 4);
    lx = prow[720 + idx]; ly = prow[720 + 144 + idx]; lz = prow[720 + 288 + idx];
  }
  const float* R = rot + i * 9;
  const float* tr = trans + i * 3;
  float gx = R[0]*lx + R[1]*ly + R[2]*lz + tr[0];
  float gy = R[3]*lx + R[4]*ly + R[5]*lz + tr[1];
  float gz = R[6]*lx + R[7]*ly + R[8]*lz + tr[2];
  if (pp < 4) {
    float* q = qpts + i*144 + h*12 + pp*3;
    q[0] = gx; q[1] = gy; q[2] = gz;
  } else {
    int p = pp - 4;
    if (p < 4) { float* o = kpts + (h*L_ + i)*12 + p*3;     o[0]=gx; o[1]=gy; o[2]=gz; }
    else       { float* o = vpts + (h*L_ + i)*24 + (p-4)*3; o[0]=gx; o[1]=gy; o[2]=gz; }
  }
}

// ---------------- K4: sparse edge bias ----------------
__global__ __launch_bounds__(256) void bias_edge_kernel(const float* __restrict__ z,
                                                        const float* __restrict__ Wb,
                                                        float* __restrict__ bias_e) {
  int i = blockIdx.x;
  __shared__ float zs[NB_ * 129];    // stride 129: conflict-free
  __shared__ float wbs[Cz_ * H_];
  int t = threadIdx.x;
  for (int e = t; e < NB_ * Cz_; e += 256) { int k = e >> 7, c = e & 127; zs[k * 129 + c] = z[i * NB_ * Cz_ + e]; }
  for (int e = t; e < Cz_ * H_; e += 256) wbs[e] = Wb[e];
  __syncthreads();
  for (int o = t; o < NB_ * H_; o += 256) {
    int k = o / H_, hh = o % H_;
    float a0 = 0.f, a1 = 0.f, a2 = 0.f, a3 = 0.f;
    #pragma unroll
    for (int c = 0; c < 128; c += 4) {
      a0 += zs[k*129 + c    ] * wbs[(c    ) * H_ + hh];
      a1 += zs[k*129 + c + 1] * wbs[(c + 1) * H_ + hh];
      a2 += zs[k*129 + c + 2] * wbs[(c + 2) * H_ + hh];
      a3 += zs[k*129 + c + 3] * wbs[(c + 3) * H_ + hh];
    }
    bias_e[i * NB_ * H_ + o] = SQRT3INV * ((a0 + a1) + (a2 + a3));
  }
}

// ---------------- K5: fused attention ----------------
#define TI 8
#define ST4(dst, c0, v) dst[(c0)*264+t]=v.x; dst[((c0)+1)*264+t]=v.y; dst[((c0)+2)*264+t]=v.z; dst[((c0)+3)*264+t]=v.w

__global__ __launch_bounds__(256) void attn_kernel(
    const float* __restrict__ proj,    // [768][1152]
    const float* __restrict__ qpts,    // [768][12][12]
    const float* __restrict__ kpts,    // [12][768][12]
    const float* __restrict__ vpts,    // [12][768][24]
    const float* __restrict__ bias_e,  // [768][30][12]
    const int*   __restrict__ E_idx,   // [768][30]
    const float* __restrict__ rot,     // [768][9]
    const float* __restrict__ trans,   // [768][3]
    const float* __restrict__ maskp,   // [768]
    const float* __restrict__ z,       // [768][30][128]
    const float* __restrict__ head_w,  // [12]
    const float* __restrict__ b_b,     // [12]
    short* __restrict__ catb)          // [768][2112] bf16
{
  const int h = blockIdx.y;
  const int i0 = blockIdx.x * TI;
  const int t = threadIdx.x;
  const int lane = t & 31, grp = t >> 5;
  const int i = i0 + grp;

  __shared__ __align__(16) float S[TI][L_];   // 24KB
  __shared__ __align__(16) float U[10560];    // 42.24KB: kcT/kpT/mc, then vcT, then reduce
  __shared__ float denom_s[TI];
  __shared__ float ew[TI][NB_];
  __shared__ int   eidx[TI][NB_];
  __shared__ float opts[TI][24];

  // hoist q / q_pts to registers (broadcast global loads, L2)
  float qreg[16], qpreg[12];
  {
    const float* qp = proj + i * PROJN + h * 16;
    #pragma unroll
    for (int c = 0; c < 16; ++c) qreg[c] = qp[c];
    const float* qpp = qpts + i * 144 + h * 12;
    #pragma unroll
    for (int c = 0; c < 12; ++c) qpreg[c] = qpp[c];
  }
  for (int e = t; e < TI * NB_; e += 256) { int ti = e / NB_, k = e % NB_; eidx[ti][k] = E_idx[(i0 + ti) * NB_ + k]; }
  const float mrow = maskp[i];
  const float hwh = 0.5f * log1pf(expf(head_w[h])) * WC_;
  const float bb = SQRT3INV * b_b[h];
  float4* S4g = (float4*)&S[grp][0];

  // ---- phase 1: logits (channel-major K staging, j-vectorized) ----
  const float* kbase = proj + 192 + h * 32;
  const float* kp_h  = kpts + (size_t)h * L_ * 12;
  float* kcT = U;              // [16][264]
  float* kpT = U + 16 * 264;   // [12][264]
  float* mcp = U + 28 * 264;   // [256]
  for (int chnk = 0; chnk < 3; ++chnk) {
    const int j0 = chnk * 256;
    __syncthreads();
    {
      const float4* kr = (const float4*)(kbase + (size_t)(j0 + t) * PROJN);
      float4 k0v = kr[0], k1v = kr[1], k2v = kr[2], k3v = kr[3];
      ST4(kcT, 0, k0v); ST4(kcT, 4, k1v); ST4(kcT, 8, k2v); ST4(kcT, 12, k3v);
      const float4* pr = (const float4*)(kp_h + (size_t)(j0 + t) * 12);
      float4 p0 = pr[0], p1 = pr[1], p2 = pr[2];
      ST4(kpT, 0, p0); ST4(kpT, 4, p1); ST4(kpT, 8, p2);
      mcp[t] = maskp[j0 + t];
    }
    __syncthreads();
    const float4* kcT4 = (const float4*)kcT;   // row stride 66 float4
    const float4* kpT4 = (const float4*)kpT;
    const float4* mc4  = (const float4*)mcp;
    #pragma unroll
    for (int half = 0; half < 2; ++half) {
      const int jb = lane + half * 32;
      float qk0=0.f,qk1=0.f,qk2=0.f,qk3=0.f;
      #pragma unroll
      for (int c = 0; c < 16; ++c) {
        float4 kv = kcT4[c * 66 + jb];
        qk0 += qreg[c]*kv.x; qk1 += qreg[c]*kv.y; qk2 += qreg[c]*kv.z; qk3 += qreg[c]*kv.w;
      }
      float ss0=0.f,ss1=0.f,ss2=0.f,ss3=0.f;
      #pragma unroll
      for (int c = 0; c < 12; ++c) {
        float4 kv = kpT4[c * 66 + jb];
        float d0=qpreg[c]-kv.x, d1=qpreg[c]-kv.y, d2=qpreg[c]-kv.z, d3=qpreg[c]-kv.w;
        ss0+=d0*d0; ss1+=d1*d1; ss2+=d2*d2; ss3+=d3*d3;
      }
      float4 mv = mc4[jb];
      float4 o;
      o.x = qk0*SCALE_QK - hwh*ss0 + bb + INF_*(mrow*mv.x-1.0f);
      o.y = qk1*SCALE_QK - hwh*ss1 + bb + INF_*(mrow*mv.y-1.0f);
      o.z = qk2*SCALE_QK - hwh*ss2 + bb + INF_*(mrow*mv.z-1.0f);
      o.w = qk3*SCALE_QK - hwh*ss3 + bb + INF_*(mrow*mv.w-1.0f);
      S4g[(j0 >> 2) + jb] = o;
    }
  }
  __syncthreads();

  // ---- phase 2: sparse edge bias scatter ----
  if (t < TI * NB_) {
    int ti = t / NB_, k = t % NB_;
    S[ti][eidx[ti][k]] += bias_e[(i0 + ti) * NB_ * H_ + k * H_ + h];
  }
  __syncthreads();

  // ---- phase 3: softmax (unnormalized) ----
  {
    float mx = -1e30f;
    #pragma unroll
    for (int rr = 0; rr < 6; ++rr) {
      float4 v = S4g[lane + rr * 32];
      mx = fmaxf(mx, fmaxf(fmaxf(v.x, v.y), fmaxf(v.z, v.w)));
    }
    #pragma unroll
    for (int d = 16; d; d >>= 1) mx = fmaxf(mx, __shfl_xor(mx, d, 32));
    float sum = 0.f;
    #pragma unroll
    for (int rr = 0; rr < 6; ++rr) {
      float4 v = S4g[lane + rr * 32];
      v.x = expf(v.x - mx); v.y = expf(v.y - mx); v.z = expf(v.z - mx); v.w = expf(v.w - mx);
      S4g[lane + rr * 32] = v;
      sum += (v.x + v.y) + (v.z + v.w);
    }
    #pragma unroll
    for (int d = 16; d; d >>= 1) sum += __shfl_xor(sum, d, 32);
    if (lane == 0) denom_s[grp] = sum;
  }
  __syncthreads();
  if (t < TI * NB_) { int ti = t / NB_, k = t % NB_; ew[ti][k] = S[ti][eidx[ti][k]]; }

  // ---- phase 4: o + o_pt sums, j-parallel with 40 independent accumulators ----
  float acc[40];
  #pragma unroll
  for (int c = 0; c < 40; ++c) acc[c] = 0.f;
  const float* vbase = proj + 192 + h * 32 + 16;
  const float* vp_h  = vpts + (size_t)h * L_ * 24;
  for (int chnk = 0; chnk < 3; ++chnk) {
    const int j0 = chnk * 256;
    __syncthreads();
    {
      const float4* vr = (const float4*)(vbase + (size_t)(j0 + t) * PROJN);
      float4 a0 = vr[0], a1 = vr[1], a2 = vr[2], a3 = vr[3];
      ST4(U, 0, a0); ST4(U, 4, a1); ST4(U, 8, a2); ST4(U, 12, a3);
      const float4* pr = (const float4*)(vp_h + (size_t)(j0 + t) * 24);
      float4 b0 = pr[0], b1 = pr[1], b2 = pr[2], b3 = pr[3], b4 = pr[4], b5 = pr[5];
      ST4(U, 16, b0); ST4(U, 20, b1); ST4(U, 24, b2);
      ST4(U, 28, b3); ST4(U, 32, b4); ST4(U, 36, b5);
    }
    __syncthreads();
    float4 p0 = S4g[(j0 >> 2) + lane];
    float4 p1 = S4g[(j0 >> 2) + 32 + lane];
    #pragma unroll
    for (int c = 0; c < 40; ++c) {
      const float4* vrow = (const float4*)(U + c * 264);
      float4 v0 = vrow[lane], v1 = vrow[32 + lane];
      acc[c] += p0.x*v0.x + p0.y*v0.y + p0.z*v0.z + p0.w*v0.w
              + p1.x*v1.x + p1.y*v1.y + p1.z*v1.z + p1.w*v1.w;
    }
  }
  __syncthreads();
  // write partials (stride 33: conflict-free), reduce
  #pragma unroll
  for (int c = 0; c < 40; ++c) U[(grp * 40 + c) * 33 + lane] = acc[c];
  __syncthreads();
  for (int o = t; o < TI * 40; o += 256) {
    int g = o / 40, c = o % 40;
    const float* rr = U + o * 33;
    float s0=0.f,s1=0.f,s2=0.f,s3=0.f;
    #pragma unroll
    for (int x = 0; x < 32; x += 4) { s0 += rr[x]; s1 += rr[x+1]; s2 += rr[x+2]; s3 += rr[x+3]; }
    float s = (s0+s1)+(s2+s3);
    if (c < 16) catb[(size_t)(i0 + g) * CONCAT_ + h * 16 + c] = f2b(s / denom_s[g]);
    else opts[g][c - 16] = s;
  }
  __syncthreads();

  // ---- phase 4b: inverse-rotate o_pt, norms ----
  if (t < TI * 8) {
    int ti = t >> 3, p = t & 7;
    int ii = i0 + ti;
    float di = 1.0f / denom_s[ti];
    const float* tr = trans + ii * 3;
    float gx = opts[ti][p * 3 + 0] * di - tr[0];
    float gy = opts[ti][p * 3 + 1] * di - tr[1];
    float gz = opts[ti][p * 3 + 2] * di - tr[2];
    const float* R = rot + ii * 9;
    float lx = R[0] * gx + R[3] * gy + R[6] * gz;
    float ly = R[1] * gx + R[4] * gy + R[7] * gz;
    float lz = R[2] * gx + R[5] * gy + R[8] * gz;
    float nrm = sqrtf(lx * lx + ly * ly + lz * lz + 1e-8f);
    short* crow = catb + (size_t)ii * CONCAT_;
    crow[192 + h * 8 + p] = f2b(lx);
    crow[288 + h * 8 + p] = f2b(ly);
    crow[384 + h * 8 + p] = f2b(lz);
    crow[480 + h * 8 + p] = f2b(nrm);
  }

  // ---- phase 5: sparse o_pair ----
  {
    const float* zrow = z + (size_t)i * NB_ * Cz_;
    const float dinv = 1.0f / denom_s[grp];
    float a0 = 0.f, a1 = 0.f, a2 = 0.f, a3 = 0.f;
    #pragma unroll 5
    for (int k = 0; k < NB_; ++k) {
      float w = ew[grp][k];
      const float* zp = zrow + k * Cz_;
      a0 += w * zp[lane];
      a1 += w * zp[lane + 32];
      a2 += w * zp[lane + 64];
      a3 += w * zp[lane + 96];
    }
    short* crow = catb + (size_t)i * CONCAT_ + 576 + h * Cz_;
    crow[lane]      = f2b(a0 * dinv);
    crow[lane + 32] = f2b(a1 * dinv);
    crow[lane + 64] = f2b(a2 * dinv);
    crow[lane + 96] = f2b(a3 * dinv);
  }
}

// ---------------- K6a: W_out -> bf16 transposed [384][2112] ----------------
__global__ __launch_bounds__(256) void cvt_wout(const float* __restrict__ W, short* __restrict__ Wt) {
  __shared__ float tile[32][33];
  const int k0 = blockIdx.x * 32, n0 = blockIdx.y * 32;
  const int tn = threadIdx.x & 31, tk = threadIdx.x >> 5;
  #pragma unroll
  for (int kk = tk; kk < 32; kk += 8)
    tile[kk][tn] = W[(size_t)(k0 + kk) * Cs_ + n0 + tn];
  __syncthreads();
  #pragma unroll
  for (int rr = tk; rr < 32; rr += 8)
    Wt[(size_t)(n0 + rr) * CONCAT_ + k0 + tn] = f2b(tile[tn][rr]);
}

// ---------------- K6b: bf16 MFMA out-GEMM: C = catb @ W_out + b_out ----------------
// one wave per 16x16 C-tile; fragments loaded directly from global (L2-resident)
__global__ __launch_bounds__(64) void gemm_out_mfma(const short* __restrict__ A,   // [768][2112]
                                                    const short* __restrict__ Bt,  // [384][2112]
                                                    const float* __restrict__ bias,
                                                    float* __restrict__ C) {
  const int l = threadIdx.x;
  const int r = l & 15, kg = l >> 4;
  const int m0 = blockIdx.x * 16, n0 = blockIdx.y * 16;
  const short* ap = A  + (size_t)(m0 + r) * CONCAT_ + kg * 8;
  const short* bp = Bt + (size_t)(n0 + r) * CONCAT_ + kg * 8;
  f32x4 acc = {0.f, 0.f, 0.f, 0.f};
  #pragma unroll 6
  for (int k = 0; k < 66; ++k) {
    bf16x8 af = *(const bf16x8*)(ap + k * 32);
    bf16x8 bf = *(const bf16x8*)(bp + k * 32);
    acc = __builtin_amdgcn_mfma_f32_16x16x32_bf16(af, bf, acc, 0, 0, 0);
  }
  const float bv = bias[n0 + r];
  #pragma unroll
  for (int j = 0; j < 4; ++j)
    C[(size_t)(m0 + kg * 4 + j) * Cs_ + n0 + r] = acc[j] + bv;
}

// ---------------- launch ----------------
extern "C" void kernel_launch(void* const* d_in, const int* in_sizes, int n_in,
                              void* d_out, int out_size, void* d_ws, size_t ws_size,
                              hipStream_t stream) {
  const float* s      = (const float*)d_in[0];
  const float* z      = (const float*)d_in[1];
  const float* rot    = (const float*)d_in[2];
  const float* trans  = (const float*)d_in[3];
  const float* mask   = (const float*)d_in[4];
  const int*   E      = (const int*)  d_in[5];
  const float* W_q    = (const float*)d_in[6];
  const float* b_q    = (const float*)d_in[7];
  const float* W_kv   = (const float*)d_in[8];
  const float* b_kv   = (const float*)d_in[9];
  const float* W_qp   = (const float*)d_in[10];
  const float* b_qp   = (const float*)d_in[11];
  const float* W_kvp  = (const float*)d_in[12];
  const float* b_kvp  = (const float*)d_in[13];
  const float* W_b    = (const float*)d_in[14];
  const float* b_b    = (const float*)d_in[15];
  const float* head_w = (const float*)d_in[16];
  const float* W_out  = (const float*)d_in[17];
  const float* b_out  = (const float*)d_in[18];

  float* ws = (float*)d_ws;
  float* Wall   = ws;                 // 442368
  float* ball   = ws + 442368;        // 1152
  float* proj   = ws + 443520;        // 884736
  float* qpts   = ws + 1328256;       // 110592
  float* kpts   = ws + 1438848;       // 110592
  float* vpts   = ws + 1549440;       // 221184
  float* bias_e = ws + 1770624;       // 276480
  short* catb   = (short*)(ws + 2047104);   // 768*2112 bf16 = 811008 float-slots
  short* WoutT  = (short*)(ws + 2858112);   // 384*2112 bf16 = 405504 float-slots
  // total 3263616 floats = 13.05 MB

  pack_kernel<<<(Cs_ * PROJN + PROJN + 255) / 256, 256, 0, stream>>>(
      W_q, b_q, W_kv, b_kv, W_qp, b_qp, W_kvp, b_kvp, Wall, ball);

  gemm_f32<32, 64, 32, 2, 4><<<dim3(L_ / 32, PROJN / 64), 256, 0, stream>>>(
      s, Wall, ball, proj, L_, PROJN, Cs_);

  pointize<<<(L_ * 192 + 255) / 256, 256, 0, stream>>>(proj, rot, trans, qpts, kpts, vpts);

  bias_edge_kernel<<<L_, 256, 0, stream>>>(z, W_b, bias_e);

  cvt_wout<<<dim3(CONCAT_ / 32, Cs_ / 32), 256, 0, stream>>>(W_out, WoutT);

  attn_kernel<<<dim3(L_ / TI, H_), 256, 0, stream>>>(
      proj, qpts, kpts, vpts, bias_e, E, rot, trans, mask, z, head_w, b_b, catb);

  gemm_out_mfma<<<dim3(L_ / 16, Cs_ / 16), 64, 0, stream>>>(catb, WoutT, b_out, (float*)d_out);
}

// Round 7
// 192.591 us; speedup vs baseline: 3.0736x; 1.4046x over previous
//
#include <hip/hip_runtime.h>
#include <hip/hip_bf16.h>
#include <math.h>

// Problem constants
#define L_    768
#define Cs_   384
#define Cz_   128
#define H_    12
#define NB_   30
#define CONCAT_ 2112
#define PROJN 1152   // 192 q + 384 kv + 144 qp + 432 kvp

#define SCALE_QK  0.14433756729740643f   // sqrt(1/48)
#define SQRT3INV  0.5773502691896258f    // sqrt(1/3)
#define WC_       0.13608276348795434f   // sqrt(1/54)
#define INF_      100000.0f

typedef short bf16x8 __attribute__((ext_vector_type(8)));
typedef float f32x4 __attribute__((ext_vector_type(4)));

__device__ __forceinline__ short f2b(float f) {
  __hip_bfloat16 b = __float2bfloat16(f);
  return *reinterpret_cast<short*>(&b);
}
__device__ __forceinline__ float b2f(short s) {
  __hip_bfloat16 b;
  *reinterpret_cast<short*>(&b) = s;
  return __bfloat162float(b);
}

// ---------------- K1: pack projection weights -> bf16 transposed [1152][384] ----------------
__global__ void pack_kernel(const float* __restrict__ Wq, const float* __restrict__ bq,
                            const float* __restrict__ Wkv, const float* __restrict__ bkv,
                            const float* __restrict__ Wqp, const float* __restrict__ bqp,
                            const float* __restrict__ Wkvp, const float* __restrict__ bkvp,
                            short* __restrict__ WallT, float* __restrict__ ball) {
  int e = blockIdx.x * 256 + threadIdx.x;
  if (e < Cs_ * PROJN) {
    int col = e / 384, kk = e % 384;
    float v;
    if (col < 192)      v = Wq[kk*192 + col];
    else if (col < 576) v = Wkv[kk*384 + (col-192)];
    else if (col < 720) v = Wqp[kk*144 + (col-576)];
    else                v = Wkvp[kk*432 + (col-720)];
    WallT[e] = f2b(v);
  } else if (e < Cs_ * PROJN + PROJN) {
    int col = e - Cs_ * PROJN;
    float v;
    if (col < 192)      v = bq[col];
    else if (col < 576) v = bkv[col-192];
    else if (col < 720) v = bqp[col-576];
    else                v = bkvp[col-720];
    ball[col] = v;
  }
}

// ---------------- K2: s -> bf16 ----------------
__global__ void cvt_s(const float* __restrict__ s, short* __restrict__ sb) {
  int e = blockIdx.x * 256 + threadIdx.x;
  if (e < L_ * Cs_) sb[e] = f2b(s[e]);
}

// ---------------- K3: proj GEMM via MFMA: proj = s @ Wall + ball (f32 out) ----------------
__global__ __launch_bounds__(64) void proj_mfma(const short* __restrict__ A,   // [768][384]
                                                const short* __restrict__ Bt,  // [1152][384]
                                                const float* __restrict__ bias,
                                                float* __restrict__ C) {
  const int l = threadIdx.x, r = l & 15, kg = l >> 4;
  const int m0 = blockIdx.x * 16, n0 = blockIdx.y * 16;
  const short* ap = A  + (size_t)(m0 + r) * 384 + kg * 8;
  const short* bp = Bt + (size_t)(n0 + r) * 384 + kg * 8;
  f32x4 acc = {0.f, 0.f, 0.f, 0.f};
  #pragma unroll
  for (int k = 0; k < 12; ++k) {
    bf16x8 af = *(const bf16x8*)(ap + k * 32);
    bf16x8 bf = *(const bf16x8*)(bp + k * 32);
    acc = __builtin_amdgcn_mfma_f32_16x16x32_bf16(af, bf, acc, 0, 0, 0);
  }
  const float bv = bias[n0 + r];
  #pragma unroll
  for (int j = 0; j < 4; ++j)
    C[(size_t)(m0 + kg * 4 + j) * PROJN + n0 + r] = acc[j] + bv;
}

// ---------------- K4: prep Amat/Bmat/VmatT/colbias ----------------
// Amat[h][i][64]: [SCALE*q(16) | xh(12) | xh(12) | xl(12) | xl(12)]  x = c2*qp_global
// Bmat[h][j][64]: [k(16)       | kh(12) | kl(12) | kh(12) | kl(12)]  kp_global hi/lo
// VmatT[h][64][768]: ch 0..15 v, 16..39 vp_hi, 40..63 vp_lo
// colbias[h][j] = -0.5*c2*|kp_j|^2 + INF*(mask_j - 1)
__global__ __launch_bounds__(256) void prep_kernel(const float* __restrict__ proj,
                                                   const float* __restrict__ rot,
                                                   const float* __restrict__ trans,
                                                   const float* __restrict__ maskp,
                                                   const float* __restrict__ head_w,
                                                   short* __restrict__ Amat,
                                                   short* __restrict__ Bmat,
                                                   short* __restrict__ VmatT,
                                                   float* __restrict__ colbias) {
  const int h = blockIdx.x / 3;
  const int i = (blockIdx.x % 3) * 256 + threadIdx.x;
  const float* p = proj + (size_t)i * PROJN;
  const float* R = rot + i * 9;
  const float* T = trans + i * 3;
  const float c2 = log1pf(expf(head_w[h])) * WC_;
  short* arow = Amat + ((size_t)h * L_ + i) * 64;
  short* brow = Bmat + ((size_t)h * L_ + i) * 64;
  #pragma unroll
  for (int c = 0; c < 16; ++c) {
    arow[c] = f2b(p[h * 16 + c] * SCALE_QK);
    brow[c] = f2b(p[192 + h * 32 + c]);
    VmatT[((size_t)h * 64 + c) * L_ + i] = f2b(p[192 + h * 32 + 16 + c]);
  }
  // q points (4): x = c2 * global
  #pragma unroll
  for (int pt = 0; pt < 4; ++pt) {
    int idx = h * 4 + pt;
    float lx = p[576 + idx], ly = p[576 + 48 + idx], lz = p[576 + 96 + idx];
    float g[3];
    g[0] = R[0]*lx + R[1]*ly + R[2]*lz + T[0];
    g[1] = R[3]*lx + R[4]*ly + R[5]*lz + T[1];
    g[2] = R[6]*lx + R[7]*ly + R[8]*lz + T[2];
    #pragma unroll
    for (int d = 0; d < 3; ++d) {
      float x = c2 * g[d];
      short xh = f2b(x);
      short xl = f2b(x - b2f(xh));
      arow[16 + pt*3 + d] = xh; arow[28 + pt*3 + d] = xh;
      arow[40 + pt*3 + d] = xl; arow[52 + pt*3 + d] = xl;
    }
  }
  // k points (4): raw hi/lo + |kp|^2
  float s2 = 0.f;
  #pragma unroll
  for (int pt = 0; pt < 4; ++pt) {
    int idx = h * 12 + pt;
    float lx = p[720 + idx], ly = p[720 + 144 + idx], lz = p[720 + 288 + idx];
    float g[3];
    g[0] = R[0]*lx + R[1]*ly + R[2]*lz + T[0];
    g[1] = R[3]*lx + R[4]*ly + R[5]*lz + T[1];
    g[2] = R[6]*lx + R[7]*ly + R[8]*lz + T[2];
    #pragma unroll
    for (int d = 0; d < 3; ++d) {
      s2 += g[d] * g[d];
      short kh = f2b(g[d]);
      short kl = f2b(g[d] - b2f(kh));
      brow[16 + pt*3 + d] = kh; brow[28 + pt*3 + d] = kl;
      brow[40 + pt*3 + d] = kh; brow[52 + pt*3 + d] = kl;
    }
  }
  colbias[h * L_ + i] = -0.5f * c2 * s2 + INF_ * (maskp[i] - 1.0f);
  // v points (8): hi/lo
  #pragma unroll
  for (int pt = 4; pt < 12; ++pt) {
    int idx = h * 12 + pt;
    float lx = p[720 + idx], ly = p[720 + 144 + idx], lz = p[720 + 288 + idx];
    float g[3];
    g[0] = R[0]*lx + R[1]*ly + R[2]*lz + T[0];
    g[1] = R[3]*lx + R[4]*ly + R[5]*lz + T[1];
    g[2] = R[6]*lx + R[7]*ly + R[8]*lz + T[2];
    #pragma unroll
    for (int d = 0; d < 3; ++d) {
      int pc = (pt - 4) * 3 + d;
      short vh = f2b(g[d]);
      short vl = f2b(g[d] - b2f(vh));
      VmatT[((size_t)h * 64 + 16 + pc) * L_ + i] = vh;
      VmatT[((size_t)h * 64 + 40 + pc) * L_ + i] = vl;
    }
  }
}

// ---------------- K5: sparse edge bias (fp32 VALU, cheap) ----------------
__global__ __launch_bounds__(256) void bias_edge_kernel(const float* __restrict__ z,
                                                        const float* __restrict__ Wb,
                                                        float* __restrict__ bias_e) {
  int i = blockIdx.x;
  __shared__ float zs[NB_ * 129];
  __shared__ float wbs[Cz_ * H_];
  int t = threadIdx.x;
  for (int e = t; e < NB_ * Cz_; e += 256) { int k = e >> 7, c = e & 127; zs[k * 129 + c] = z[(size_t)i * NB_ * Cz_ + e]; }
  for (int e = t; e < Cz_ * H_; e += 256) wbs[e] = Wb[e];
  __syncthreads();
  for (int o = t; o < NB_ * H_; o += 256) {
    int k = o / H_, hh = o % H_;
    float a0 = 0.f, a1 = 0.f, a2 = 0.f, a3 = 0.f;
    #pragma unroll
    for (int c = 0; c < 128; c += 4) {
      a0 += zs[k*129 + c    ] * wbs[(c    ) * H_ + hh];
      a1 += zs[k*129 + c + 1] * wbs[(c + 1) * H_ + hh];
      a2 += zs[k*129 + c + 2] * wbs[(c + 2) * H_ + hh];
      a3 += zs[k*129 + c + 3] * wbs[(c + 3) * H_ + hh];
    }
    bias_e[(size_t)i * NB_ * H_ + o] = SQRT3INV * ((a0 + a1) + (a2 + a3));
  }
}

// ---------------- K6: fused MFMA attention ----------------
// block = (head, 16-row tile), 4 waves of 64.
#define SLS 772   // Sl row stride (16B aligned, 4 mod 32 banks)
__global__ __launch_bounds__(256) void attn_mfma(
    const short* __restrict__ Amat,    // [12][768][64]
    const short* __restrict__ Bmat,    // [12][768][64]
    const short* __restrict__ VmatT,   // [12][64][768]
    const float* __restrict__ colbias, // [12][768]
    const float* __restrict__ bias_e,  // [768*30][12]
    const int*   __restrict__ E_idx,   // [768][30]
    const float* __restrict__ rot,     // [768][9]
    const float* __restrict__ trans,   // [768][3]
    const float* __restrict__ z,       // [768][30][128]
    short* __restrict__ catb)          // [768][2112] bf16
{
  const int h = blockIdx.y;
  const int i0 = blockIdx.x * 16;
  const int t = threadIdx.x;
  const int lane = t & 63, wave = t >> 6;
  const int fr = lane & 15, kg = lane >> 4;   // fragment row/col, k-group

  __shared__ __align__(16) float Sl[16][SLS];  // 49.4KB logits -> P
  __shared__ float ptb[16][48];
  __shared__ float ews[16][NB_];
  __shared__ int   eidx[16][NB_];
  __shared__ float denom[16];

  // A fragments for this row-tile (reused across all j)
  const short* Ab = Amat + ((size_t)h * L_ + i0 + fr) * 64 + kg * 8;
  bf16x8 a0 = *(const bf16x8*)(Ab);
  bf16x8 a1 = *(const bf16x8*)(Ab + 32);

  for (int e = t; e < 16 * NB_; e += 256)
    eidx[e / NB_][e % NB_] = E_idx[(i0 + e / NB_) * NB_ + e % NB_];

  // ---- pass 1: logits. wave w covers j in [w*192, w*192+192) ----
  #pragma unroll 3
  for (int tt = 0; tt < 12; ++tt) {
    const int j0 = wave * 192 + tt * 16;
    const short* Bb = Bmat + ((size_t)h * L_ + j0 + fr) * 64 + kg * 8;
    f32x4 acc = {0.f, 0.f, 0.f, 0.f};
    acc = __builtin_amdgcn_mfma_f32_16x16x32_bf16(a0, *(const bf16x8*)(Bb), acc, 0, 0, 0);
    acc = __builtin_amdgcn_mfma_f32_16x16x32_bf16(a1, *(const bf16x8*)(Bb + 32), acc, 0, 0, 0);
    const float cb = colbias[h * L_ + j0 + fr];
    #pragma unroll
    for (int j = 0; j < 4; ++j)
      Sl[kg * 4 + j][j0 + fr] = acc[j] + cb;
  }
  __syncthreads();

  // ---- edge bias scatter (480 elements: grid-stride, NOT t<480!) ----
  for (int e = t; e < 16 * NB_; e += 256) {
    int r = e / NB_, k = e % NB_;
    Sl[r][eidx[r][k]] += bias_e[(size_t)((i0 + r) * NB_ + k) * H_ + h];
  }
  __syncthreads();

  // ---- softmax (16 threads per row) ----
  {
    const int r = t >> 4, sub = t & 15;
    float mx = -1e30f;
    #pragma unroll
    for (int n = 0; n < 48; ++n) mx = fmaxf(mx, Sl[r][sub + n * 16]);
    #pragma unroll
    for (int d = 8; d; d >>= 1) mx = fmaxf(mx, __shfl_xor(mx, d, 16));
    float sum = 0.f;
    #pragma unroll
    for (int n = 0; n < 48; ++n) {
      float p = __expf(Sl[r][sub + n * 16] - mx);
      Sl[r][sub + n * 16] = p;
      sum += p;
    }
    #pragma unroll
    for (int d = 8; d; d >>= 1) sum += __shfl_xor(sum, d, 16);
    if (sub == 0) denom[r] = sum;
  }
  __syncthreads();

  // extract edge weights (480 elements: grid-stride)
  for (int e = t; e < 16 * NB_; e += 256) {
    int r = e / NB_, k = e % NB_;
    ews[r][k] = Sl[r][eidx[r][k]];
  }

  // ---- pass 2: PV. wave = channel tile (4 x 16ch of [v16|vph24|vpl24]) ----
  f32x4 oacc = {0.f, 0.f, 0.f, 0.f};
  const short* Vb = VmatT + ((size_t)h * 64 + wave * 16 + fr) * L_ + kg * 8;
  #pragma unroll 4
  for (int ks = 0; ks < 24; ++ks) {
    const float* sp = &Sl[fr][ks * 32 + kg * 8];
    float4 u = *(const float4*)sp;
    float4 v = *(const float4*)(sp + 4);
    bf16x8 pa;
    pa[0] = f2b(u.x); pa[1] = f2b(u.y); pa[2] = f2b(u.z); pa[3] = f2b(u.w);
    pa[4] = f2b(v.x); pa[5] = f2b(v.y); pa[6] = f2b(v.z); pa[7] = f2b(v.w);
    bf16x8 vb = *(const bf16x8*)(Vb + ks * 32);
    oacc = __builtin_amdgcn_mfma_f32_16x16x32_bf16(pa, vb, oacc, 0, 0, 0);
  }
  // epilogue: wave0 -> o channels; waves 1-3 -> point partials
  if (wave == 0) {
    #pragma unroll
    for (int j = 0; j < 4; ++j) {
      int r = kg * 4 + j;
      catb[(size_t)(i0 + r) * CONCAT_ + h * 16 + fr] = f2b(oacc[j] / denom[r]);
    }
  } else {
    int ch = wave * 16 + fr;
    int dest = (ch < 40) ? (ch - 16) : (24 + ch - 40);
    #pragma unroll
    for (int j = 0; j < 4; ++j)
      ptb[kg * 4 + j][dest] = oacc[j];
  }
  __syncthreads();

  // ---- rotate o_pt back, norms ----
  if (t < 128) {
    int r = t >> 3, pt = t & 7;
    int ii = i0 + r;
    float di = 1.0f / denom[r];
    const float* T = trans + ii * 3;
    float gx = (ptb[r][pt * 3 + 0] + ptb[r][24 + pt * 3 + 0]) * di - T[0];
    float gy = (ptb[r][pt * 3 + 1] + ptb[r][24 + pt * 3 + 1]) * di - T[1];
    float gz = (ptb[r][pt * 3 + 2] + ptb[r][24 + pt * 3 + 2]) * di - T[2];
    const float* R = rot + ii * 9;
    float lx = R[0] * gx + R[3] * gy + R[6] * gz;
    float ly = R[1] * gx + R[4] * gy + R[7] * gz;
    float lz = R[2] * gx + R[5] * gy + R[8] * gz;
    float nrm = sqrtf(lx * lx + ly * ly + lz * lz + 1e-8f);
    short* crow = catb + (size_t)ii * CONCAT_;
    crow[192 + h * 8 + pt] = f2b(lx);
    crow[288 + h * 8 + pt] = f2b(ly);
    crow[384 + h * 8 + pt] = f2b(lz);
    crow[480 + h * 8 + pt] = f2b(nrm);
  }

  // ---- sparse o_pair: 16 threads per row, 8 channels each ----
  {
    const int r = t >> 4, sub = t & 15;
    const int ii = i0 + r;
    const float di = 1.0f / denom[r];
    float accs[8];
    #pragma unroll
    for (int n = 0; n < 8; ++n) accs[n] = 0.f;
    #pragma unroll 5
    for (int k = 0; k < NB_; ++k) {
      float w = ews[r][k];
      const float* zp = z + ((size_t)ii * NB_ + k) * Cz_ + sub;
      #pragma unroll
      for (int n = 0; n < 8; ++n) accs[n] += w * zp[n * 16];
    }
    short* crow = catb + (size_t)ii * CONCAT_ + 576 + h * Cz_;
    #pragma unroll
    for (int n = 0; n < 8; ++n) crow[sub + n * 16] = f2b(accs[n] * di);
  }
}

// ---------------- K7: W_out -> bf16 transposed [384][2112] ----------------
__global__ __launch_bounds__(256) void cvt_wout(const float* __restrict__ W, short* __restrict__ Wt) {
  __shared__ float tile[32][33];
  const int k0 = blockIdx.x * 32, n0 = blockIdx.y * 32;
  const int tn = threadIdx.x & 31, tk = threadIdx.x >> 5;
  #pragma unroll
  for (int kk = tk; kk < 32; kk += 8)
    tile[kk][tn] = W[(size_t)(k0 + kk) * Cs_ + n0 + tn];
  __syncthreads();
  #pragma unroll
  for (int rr = tk; rr < 32; rr += 8)
    Wt[(size_t)(n0 + rr) * CONCAT_ + k0 + tn] = f2b(tile[tn][rr]);
}

// ---------------- K8: bf16 MFMA out-GEMM ----------------
__global__ __launch_bounds__(64) void gemm_out_mfma(const short* __restrict__ A,   // [768][2112]
                                                    const short* __restrict__ Bt,  // [384][2112]
                                                    const float* __restrict__ bias,
                                                    float* __restrict__ C) {
  const int l = threadIdx.x;
  const int r = l & 15, kg = l >> 4;
  const int m0 = blockIdx.x * 16, n0 = blockIdx.y * 16;
  const short* ap = A  + (size_t)(m0 + r) * CONCAT_ + kg * 8;
  const short* bp = Bt + (size_t)(n0 + r) * CONCAT_ + kg * 8;
  f32x4 acc = {0.f, 0.f, 0.f, 0.f};
  #pragma unroll 6
  for (int k = 0; k < 66; ++k) {
    bf16x8 af = *(const bf16x8*)(ap + k * 32);
    bf16x8 bf = *(const bf16x8*)(bp + k * 32);
    acc = __builtin_amdgcn_mfma_f32_16x16x32_bf16(af, bf, acc, 0, 0, 0);
  }
  const float bv = bias[n0 + r];
  #pragma unroll
  for (int j = 0; j < 4; ++j)
    C[(size_t)(m0 + kg * 4 + j) * Cs_ + n0 + r] = acc[j] + bv;
}

// ---------------- launch ----------------
extern "C" void kernel_launch(void* const* d_in, const int* in_sizes, int n_in,
                              void* d_out, int out_size, void* d_ws, size_t ws_size,
                              hipStream_t stream) {
  const float* s      = (const float*)d_in[0];
  const float* z      = (const float*)d_in[1];
  const float* rot    = (const float*)d_in[2];
  const float* trans  = (const float*)d_in[3];
  const float* mask   = (const float*)d_in[4];
  const int*   E      = (const int*)  d_in[5];
  const float* W_q    = (const float*)d_in[6];
  const float* b_q    = (const float*)d_in[7];
  const float* W_kv   = (const float*)d_in[8];
  const float* b_kv   = (const float*)d_in[9];
  const float* W_qp   = (const float*)d_in[10];
  const float* b_qp   = (const float*)d_in[11];
  const float* W_kvp  = (const float*)d_in[12];
  const float* b_kvp  = (const float*)d_in[13];
  const float* W_b    = (const float*)d_in[14];
  const float* b_b    = (const float*)d_in[15];  (void)b_b; // row-constant in softmax -> dropped
  const float* head_w = (const float*)d_in[16];
  const float* W_out  = (const float*)d_in[17];
  const float* b_out  = (const float*)d_in[18];

  // Workspace layout (float-slot offsets). Staging region [0..1254528) is
  // consumed by prep_kernel; catb/WoutT alias it afterwards (order enforced
  // by launch sequence on `stream`). Total footprint: 2424960 fs = 9.7 MB.
  float* ws = (float*)d_ws;
  short* WallT   = (short*)(ws + 0);        // 442368 sh = 221184 fs   [staging]
  float* ball    = ws + 221184;             // 1152                    [staging]
  short* sb      = (short*)(ws + 222336);   // 294912 sh = 147456 fs   [staging]
  float* proj    = ws + 369792;             // 884736                  [staging]
  short* catb    = (short*)(ws + 0);        // 1622016 sh = 811008 fs  [aliases staging head]
  short* WoutT   = (short*)(ws + 811008);   // 811008 sh = 405504 fs   [aliases proj tail]
  short* Amat    = (short*)(ws + 1254528);  // 589824 sh = 294912 fs
  short* Bmat    = (short*)(ws + 1549440);  // 294912 fs
  short* VmatT   = (short*)(ws + 1844352);  // 294912 fs
  float* colbias = ws + 2139264;            // 9216
  float* bias_e  = ws + 2148480;            // 276480 -> end 2424960 fs

  pack_kernel<<<(Cs_ * PROJN + PROJN + 255) / 256, 256, 0, stream>>>(
      W_q, b_q, W_kv, b_kv, W_qp, b_qp, W_kvp, b_kvp, WallT, ball);

  cvt_s<<<(L_ * Cs_ + 255) / 256, 256, 0, stream>>>(s, sb);

  proj_mfma<<<dim3(L_ / 16, PROJN / 16), 64, 0, stream>>>(sb, WallT, ball, proj);

  prep_kernel<<<36, 256, 0, stream>>>(proj, rot, trans, mask, head_w, Amat, Bmat, VmatT, colbias);

  // cvt_wout AFTER prep_kernel: WoutT aliases the proj region.
  cvt_wout<<<dim3(CONCAT_ / 32, Cs_ / 32), 256, 0, stream>>>(W_out, WoutT);

  bias_edge_kernel<<<L_, 256, 0, stream>>>(z, W_b, bias_e);

  attn_mfma<<<dim3(L_ / 16, H_), 256, 0, stream>>>(
      Amat, Bmat, VmatT, colbias, bias_e, E, rot, trans, z, catb);

  gemm_out_mfma<<<dim3(L_ / 16, Cs_ / 16), 64, 0, stream>>>(catb, WoutT, b_out, (float*)d_out);
}

// Round 8
// 187.222 us; speedup vs baseline: 3.1617x; 1.0287x over previous
//
#include <hip/hip_runtime.h>
#include <hip/hip_bf16.h>
#include <math.h>

// Problem constants
#define L_    768
#define Cs_   384
#define Cz_   128
#define H_    12
#define NB_   30
#define CONCAT_ 2112
#define PROJN 1152   // 192 q + 384 kv + 144 qp + 432 kvp

#define SCALE_QK  0.14433756729740643f   // sqrt(1/48)
#define SQRT3INV  0.5773502691896258f    // sqrt(1/3)
#define WC_       0.13608276348795434f   // sqrt(1/54)
#define INF_      100000.0f

typedef short bf16x8 __attribute__((ext_vector_type(8)));
typedef float f32x4 __attribute__((ext_vector_type(4)));

__device__ __forceinline__ short f2b(float f) {
  __hip_bfloat16 b = __float2bfloat16(f);
  return *reinterpret_cast<short*>(&b);
}
__device__ __forceinline__ float b2f(short s) {
  __hip_bfloat16 b;
  *reinterpret_cast<short*>(&b) = s;
  return __bfloat162float(b);
}

// ---------------- K1: pack weights -> bf16 WallT [1152][384], ball, and s -> bf16 ----------------
__global__ void pack_kernel(const float* __restrict__ Wq, const float* __restrict__ bq,
                            const float* __restrict__ Wkv, const float* __restrict__ bkv,
                            const float* __restrict__ Wqp, const float* __restrict__ bqp,
                            const float* __restrict__ Wkvp, const float* __restrict__ bkvp,
                            const float* __restrict__ s,
                            short* __restrict__ WallT, float* __restrict__ ball,
                            short* __restrict__ sb) {
  int e = blockIdx.x * 256 + threadIdx.x;
  if (e < Cs_ * PROJN) {
    int col = e / 384, kk = e % 384;
    float v;
    if (col < 192)      v = Wq[kk*192 + col];
    else if (col < 576) v = Wkv[kk*384 + (col-192)];
    else if (col < 720) v = Wqp[kk*144 + (col-576)];
    else                v = Wkvp[kk*432 + (col-720)];
    WallT[e] = f2b(v);
  } else if (e < Cs_ * PROJN + PROJN) {
    int col = e - Cs_ * PROJN;
    float v;
    if (col < 192)      v = bq[col];
    else if (col < 576) v = bkv[col-192];
    else if (col < 720) v = bqp[col-576];
    else                v = bkvp[col-720];
    ball[col] = v;
  } else if (e < Cs_ * PROJN + PROJN + L_ * Cs_) {
    int x = e - (Cs_ * PROJN + PROJN);
    sb[x] = f2b(s[x]);
  }
}

// ---------------- K2: proj GEMM via MFMA: proj = s @ Wall + ball (f32 out) ----------------
__global__ __launch_bounds__(64) void proj_mfma(const short* __restrict__ A,   // [768][384]
                                                const short* __restrict__ Bt,  // [1152][384]
                                                const float* __restrict__ bias,
                                                float* __restrict__ C) {
  const int l = threadIdx.x, r = l & 15, kg = l >> 4;
  const int m0 = blockIdx.x * 16, n0 = blockIdx.y * 16;
  const short* ap = A  + (size_t)(m0 + r) * 384 + kg * 8;
  const short* bp = Bt + (size_t)(n0 + r) * 384 + kg * 8;
  f32x4 acc = {0.f, 0.f, 0.f, 0.f};
  #pragma unroll
  for (int k = 0; k < 12; ++k) {
    bf16x8 af = *(const bf16x8*)(ap + k * 32);
    bf16x8 bf = *(const bf16x8*)(bp + k * 32);
    acc = __builtin_amdgcn_mfma_f32_16x16x32_bf16(af, bf, acc, 0, 0, 0);
  }
  const float bv = bias[n0 + r];
  #pragma unroll
  for (int j = 0; j < 4; ++j)
    C[(size_t)(m0 + kg * 4 + j) * PROJN + n0 + r] = acc[j] + bv;
}

// ---------------- K3: prep Amat/Bmat/VmatT/colbias ----------------
// Amat[h][i][64]: [SCALE*q(16) | xh(12) | xh(12) | xl(12) | xl(12)]  x = c2*qp_global
// Bmat[h][j][64]: [k(16)       | kh(12) | kl(12) | kh(12) | kl(12)]  kp_global hi/lo
// VmatT[h][64][768]: ch 0..15 v, 16..39 vp_hi, 40..63 vp_lo
// colbias[h][j] = -0.5*c2*|kp_j|^2 + INF*(mask_j - 1)
__global__ __launch_bounds__(256) void prep_kernel(const float* __restrict__ proj,
                                                   const float* __restrict__ rot,
                                                   const float* __restrict__ trans,
                                                   const float* __restrict__ maskp,
                                                   const float* __restrict__ head_w,
                                                   short* __restrict__ Amat,
                                                   short* __restrict__ Bmat,
                                                   short* __restrict__ VmatT,
                                                   float* __restrict__ colbias) {
  const int h = blockIdx.x / 3;
  const int i = (blockIdx.x % 3) * 256 + threadIdx.x;
  const float* p = proj + (size_t)i * PROJN;
  const float* R = rot + i * 9;
  const float* T = trans + i * 3;
  const float c2 = log1pf(expf(head_w[h])) * WC_;
  short* arow = Amat + ((size_t)h * L_ + i) * 64;
  short* brow = Bmat + ((size_t)h * L_ + i) * 64;
  #pragma unroll
  for (int c = 0; c < 16; ++c) {
    arow[c] = f2b(p[h * 16 + c] * SCALE_QK);
    brow[c] = f2b(p[192 + h * 32 + c]);
    VmatT[((size_t)h * 64 + c) * L_ + i] = f2b(p[192 + h * 32 + 16 + c]);
  }
  // q points (4): x = c2 * global
  #pragma unroll
  for (int pt = 0; pt < 4; ++pt) {
    int idx = h * 4 + pt;
    float lx = p[576 + idx], ly = p[576 + 48 + idx], lz = p[576 + 96 + idx];
    float g[3];
    g[0] = R[0]*lx + R[1]*ly + R[2]*lz + T[0];
    g[1] = R[3]*lx + R[4]*ly + R[5]*lz + T[1];
    g[2] = R[6]*lx + R[7]*ly + R[8]*lz + T[2];
    #pragma unroll
    for (int d = 0; d < 3; ++d) {
      float x = c2 * g[d];
      short xh = f2b(x);
      short xl = f2b(x - b2f(xh));
      arow[16 + pt*3 + d] = xh; arow[28 + pt*3 + d] = xh;
      arow[40 + pt*3 + d] = xl; arow[52 + pt*3 + d] = xl;
    }
  }
  // k points (4): raw hi/lo + |kp|^2
  float s2 = 0.f;
  #pragma unroll
  for (int pt = 0; pt < 4; ++pt) {
    int idx = h * 12 + pt;
    float lx = p[720 + idx], ly = p[720 + 144 + idx], lz = p[720 + 288 + idx];
    float g[3];
    g[0] = R[0]*lx + R[1]*ly + R[2]*lz + T[0];
    g[1] = R[3]*lx + R[4]*ly + R[5]*lz + T[1];
    g[2] = R[6]*lx + R[7]*ly + R[8]*lz + T[2];
    #pragma unroll
    for (int d = 0; d < 3; ++d) {
      s2 += g[d] * g[d];
      short kh = f2b(g[d]);
      short kl = f2b(g[d] - b2f(kh));
      brow[16 + pt*3 + d] = kh; brow[28 + pt*3 + d] = kl;
      brow[40 + pt*3 + d] = kh; brow[52 + pt*3 + d] = kl;
    }
  }
  colbias[h * L_ + i] = -0.5f * c2 * s2 + INF_ * (maskp[i] - 1.0f);
  // v points (8): hi/lo
  #pragma unroll
  for (int pt = 4; pt < 12; ++pt) {
    int idx = h * 12 + pt;
    float lx = p[720 + idx], ly = p[720 + 144 + idx], lz = p[720 + 288 + idx];
    float g[3];
    g[0] = R[0]*lx + R[1]*ly + R[2]*lz + T[0];
    g[1] = R[3]*lx + R[4]*ly + R[5]*lz + T[1];
    g[2] = R[6]*lx + R[7]*ly + R[8]*lz + T[2];
    #pragma unroll
    for (int d = 0; d < 3; ++d) {
      int pc = (pt - 4) * 3 + d;
      short vh = f2b(g[d]);
      short vl = f2b(g[d] - b2f(vh));
      VmatT[((size_t)h * 64 + 16 + pc) * L_ + i] = vh;
      VmatT[((size_t)h * 64 + 40 + pc) * L_ + i] = vl;
    }
  }
}

// ---------------- K4: edge bias via MFMA: bias_e[m][h] = sqrt(1/3) * z[m,:] @ Wb[:,h] ----------------
// m = i*30+k (23040 rows), z converted f32->bf16 in-register.
__global__ __launch_bounds__(64) void bias_mfma(const float* __restrict__ z,    // [23040][128]
                                                const float* __restrict__ Wb,   // [128][12]
                                                float* __restrict__ bias_e) {   // [23040][12]
  const int l = threadIdx.x, r = l & 15, kg = l >> 4;
  const int m0 = blockIdx.x * 16;
  f32x4 acc = {0.f, 0.f, 0.f, 0.f};
  const float* zr = z + (size_t)(m0 + r) * Cz_ + kg * 8;
  #pragma unroll
  for (int kc = 0; kc < 4; ++kc) {
    float4 a0 = *(const float4*)(zr + kc * 32);
    float4 a1 = *(const float4*)(zr + kc * 32 + 4);
    bf16x8 af, bf;
    af[0]=f2b(a0.x); af[1]=f2b(a0.y); af[2]=f2b(a0.z); af[3]=f2b(a0.w);
    af[4]=f2b(a1.x); af[5]=f2b(a1.y); af[6]=f2b(a1.z); af[7]=f2b(a1.w);
    #pragma unroll
    for (int j = 0; j < 8; ++j) {
      int k = kc * 32 + kg * 8 + j;
      bf[j] = (r < H_) ? f2b(Wb[k * H_ + r]) : (short)0;
    }
    acc = __builtin_amdgcn_mfma_f32_16x16x32_bf16(af, bf, acc, 0, 0, 0);
  }
  if (r < H_) {
    #pragma unroll
    for (int j = 0; j < 4; ++j)
      bias_e[(size_t)(m0 + kg * 4 + j) * H_ + r] = SQRT3INV * acc[j];
  }
}

// ---------------- K5: fused MFMA attention ----------------
// block = (head, 16-row tile), 4 waves of 64.
#define SLS 772   // Sl row stride (16B aligned, 4 mod 32 banks)
__global__ __launch_bounds__(256) void attn_mfma(
    const short* __restrict__ Amat,    // [12][768][64]
    const short* __restrict__ Bmat,    // [12][768][64]
    const short* __restrict__ VmatT,   // [12][64][768]
    const float* __restrict__ colbias, // [12][768]
    const float* __restrict__ bias_e,  // [768*30][12]
    const int*   __restrict__ E_idx,   // [768][30]
    const float* __restrict__ rot,     // [768][9]
    const float* __restrict__ trans,   // [768][3]
    const float* __restrict__ z,       // [768][30][128]
    short* __restrict__ catb)          // [768][2112] bf16
{
  const int h = blockIdx.y;
  const int i0 = blockIdx.x * 16;
  const int t = threadIdx.x;
  const int lane = t & 63, wave = t >> 6;
  const int fr = lane & 15, kg = lane >> 4;   // fragment row/col, k-group

  __shared__ __align__(16) float Sl[16][SLS];  // 49.4KB logits -> P(f32) -> P(bf16 in low half)
  __shared__ float ptb[16][48];
  __shared__ float ews[16][NB_];
  __shared__ int   eidx[16][NB_];
  __shared__ float denom[16];

  // A fragments for this row-tile (reused across all j)
  const short* Ab = Amat + ((size_t)h * L_ + i0 + fr) * 64 + kg * 8;
  bf16x8 a0 = *(const bf16x8*)(Ab);
  bf16x8 a1 = *(const bf16x8*)(Ab + 32);

  for (int e = t; e < 16 * NB_; e += 256)
    eidx[e / NB_][e % NB_] = E_idx[(i0 + e / NB_) * NB_ + e % NB_];

  // ---- pass 1: logits. wave w covers j in [w*192, w*192+192) ----
  #pragma unroll 3
  for (int tt = 0; tt < 12; ++tt) {
    const int j0 = wave * 192 + tt * 16;
    const short* Bb = Bmat + ((size_t)h * L_ + j0 + fr) * 64 + kg * 8;
    f32x4 acc = {0.f, 0.f, 0.f, 0.f};
    acc = __builtin_amdgcn_mfma_f32_16x16x32_bf16(a0, *(const bf16x8*)(Bb), acc, 0, 0, 0);
    acc = __builtin_amdgcn_mfma_f32_16x16x32_bf16(a1, *(const bf16x8*)(Bb + 32), acc, 0, 0, 0);
    const float cb = colbias[h * L_ + j0 + fr];
    #pragma unroll
    for (int j = 0; j < 4; ++j)
      Sl[kg * 4 + j][j0 + fr] = acc[j] + cb;
  }
  __syncthreads();

  // ---- edge bias scatter (480 elements: grid-stride) ----
  for (int e = t; e < 16 * NB_; e += 256) {
    int r = e / NB_, k = e % NB_;
    Sl[r][eidx[r][k]] += bias_e[(size_t)((i0 + r) * NB_ + k) * H_ + h];
  }
  __syncthreads();

  // ---- softmax (16 threads per row) ----
  {
    const int r = t >> 4, sub = t & 15;
    float mx = -1e30f;
    #pragma unroll
    for (int n = 0; n < 48; ++n) mx = fmaxf(mx, Sl[r][sub + n * 16]);
    #pragma unroll
    for (int d = 8; d; d >>= 1) mx = fmaxf(mx, __shfl_xor(mx, d, 16));
    float sum = 0.f;
    #pragma unroll
    for (int n = 0; n < 48; ++n) {
      float p = __expf(Sl[r][sub + n * 16] - mx);
      Sl[r][sub + n * 16] = p;
      sum += p;
    }
    #pragma unroll
    for (int d = 8; d; d >>= 1) sum += __shfl_xor(sum, d, 16);
    if (sub == 0) denom[r] = sum;
  }
  __syncthreads();

  // extract edge weights (reads Sl f32) + stage convert reads in regs
  for (int e = t; e < 16 * NB_; e += 256) {
    int r = e / NB_, k = e % NB_;
    ews[r][k] = Sl[r][eidx[r][k]];
  }
  // ---- in-place P f32 -> bf16 (packed into first half of each Sl row) ----
  {
    const int cr = t & 15;           // row
    const int cc = (t >> 4) * 48;    // col start
    float v[48];
    #pragma unroll
    for (int n = 0; n < 12; ++n) {
      float4 u = *(const float4*)&Sl[cr][cc + n * 4];
      v[n*4+0] = u.x; v[n*4+1] = u.y; v[n*4+2] = u.z; v[n*4+3] = u.w;
    }
    __syncthreads();   // all reads (ews + v[]) done before overwrite
    unsigned* dst = (unsigned*)&Sl[cr][0];
    #pragma unroll
    for (int n = 0; n < 24; ++n) {
      unsigned lo = (unsigned short)f2b(v[2*n]);
      unsigned hi = (unsigned short)f2b(v[2*n+1]);
      dst[cc/2 + n] = lo | (hi << 16);
    }
  }
  __syncthreads();

  // ---- pass 2: PV. wave = channel tile (4 x 16ch of [v16|vph24|vpl24]) ----
  f32x4 oacc = {0.f, 0.f, 0.f, 0.f};
  const short* Vb = VmatT + ((size_t)h * 64 + wave * 16 + fr) * L_ + kg * 8;
  const short* PbRow = (const short*)&Sl[fr][0];
  #pragma unroll 4
  for (int ks = 0; ks < 24; ++ks) {
    bf16x8 pa = *(const bf16x8*)(PbRow + ks * 32 + kg * 8);
    bf16x8 vb = *(const bf16x8*)(Vb + ks * 32);
    oacc = __builtin_amdgcn_mfma_f32_16x16x32_bf16(pa, vb, oacc, 0, 0, 0);
  }
  // epilogue: wave0 -> o channels; waves 1-3 -> point partials
  if (wave == 0) {
    #pragma unroll
    for (int j = 0; j < 4; ++j) {
      int r = kg * 4 + j;
      catb[(size_t)(i0 + r) * CONCAT_ + h * 16 + fr] = f2b(oacc[j] / denom[r]);
    }
  } else {
    int ch = wave * 16 + fr;
    int dest = (ch < 40) ? (ch - 16) : (24 + ch - 40);
    #pragma unroll
    for (int j = 0; j < 4; ++j)
      ptb[kg * 4 + j][dest] = oacc[j];
  }
  __syncthreads();

  // ---- rotate o_pt back, norms ----
  if (t < 128) {
    int r = t >> 3, pt = t & 7;
    int ii = i0 + r;
    float di = 1.0f / denom[r];
    const float* T = trans + ii * 3;
    float gx = (ptb[r][pt * 3 + 0] + ptb[r][24 + pt * 3 + 0]) * di - T[0];
    float gy = (ptb[r][pt * 3 + 1] + ptb[r][24 + pt * 3 + 1]) * di - T[1];
    float gz = (ptb[r][pt * 3 + 2] + ptb[r][24 + pt * 3 + 2]) * di - T[2];
    const float* R = rot + ii * 9;
    float lx = R[0] * gx + R[3] * gy + R[6] * gz;
    float ly = R[1] * gx + R[4] * gy + R[7] * gz;
    float lz = R[2] * gx + R[5] * gy + R[8] * gz;
    float nrm = sqrtf(lx * lx + ly * ly + lz * lz + 1e-8f);
    short* crow = catb + (size_t)ii * CONCAT_;
    crow[192 + h * 8 + pt] = f2b(lx);
    crow[288 + h * 8 + pt] = f2b(ly);
    crow[384 + h * 8 + pt] = f2b(lz);
    crow[480 + h * 8 + pt] = f2b(nrm);
  }

  // ---- sparse o_pair: 16 threads per row, 8 channels each ----
  {
    const int r = t >> 4, sub = t & 15;
    const int ii = i0 + r;
    const float di = 1.0f / denom[r];
    float accs[8];
    #pragma unroll
    for (int n = 0; n < 8; ++n) accs[n] = 0.f;
    #pragma unroll 5
    for (int k = 0; k < NB_; ++k) {
      float w = ews[r][k];
      const float* zp = z + ((size_t)ii * NB_ + k) * Cz_ + sub;
      #pragma unroll
      for (int n = 0; n < 8; ++n) accs[n] += w * zp[n * 16];
    }
    short* crow = catb + (size_t)ii * CONCAT_ + 576 + h * Cz_;
    #pragma unroll
    for (int n = 0; n < 8; ++n) crow[sub + n * 16] = f2b(accs[n] * di);
  }
}

// ---------------- K6: W_out -> bf16 transposed [384][2112] ----------------
__global__ __launch_bounds__(256) void cvt_wout(const float* __restrict__ W, short* __restrict__ Wt) {
  __shared__ float tile[32][33];
  const int k0 = blockIdx.x * 32, n0 = blockIdx.y * 32;
  const int tn = threadIdx.x & 31, tk = threadIdx.x >> 5;
  #pragma unroll
  for (int kk = tk; kk < 32; kk += 8)
    tile[kk][tn] = W[(size_t)(k0 + kk) * Cs_ + n0 + tn];
  __syncthreads();
  #pragma unroll
  for (int rr = tk; rr < 32; rr += 8)
    Wt[(size_t)(n0 + rr) * CONCAT_ + k0 + tn] = f2b(tile[tn][rr]);
}

// ---------------- K7: bf16 MFMA out-GEMM, 4-wave k-split ----------------
__global__ __launch_bounds__(256) void gemm_out_mfma(const short* __restrict__ A,   // [768][2112]
                                                     const short* __restrict__ Bt,  // [384][2112]
                                                     const float* __restrict__ bias,
                                                     float* __restrict__ C) {
  const int t = threadIdx.x;
  const int w = t >> 6, l = t & 63;
  const int r = l & 15, kg = l >> 4;
  const int m0 = blockIdx.x * 16, n0 = blockIdx.y * 16;
  __shared__ float part[4][16][17];
  const int kcnt = (w < 2) ? 17 : 16;                 // 66 = 17+17+16+16 K-chunks of 32
  const int koff = (w < 2) ? w * 17 : 34 + (w - 2) * 16;
  const short* ap = A  + (size_t)(m0 + r) * CONCAT_ + koff * 32 + kg * 8;
  const short* bp = Bt + (size_t)(n0 + r) * CONCAT_ + koff * 32 + kg * 8;
  f32x4 acc = {0.f, 0.f, 0.f, 0.f};
  #pragma unroll 4
  for (int k = 0; k < kcnt; ++k) {
    bf16x8 af = *(const bf16x8*)(ap + k * 32);
    bf16x8 bf = *(const bf16x8*)(bp + k * 32);
    acc = __builtin_amdgcn_mfma_f32_16x16x32_bf16(af, bf, acc, 0, 0, 0);
  }
  #pragma unroll
  for (int j = 0; j < 4; ++j) part[w][kg * 4 + j][r] = acc[j];
  __syncthreads();
  const int row = t >> 4, col = t & 15;
  float sum = part[0][row][col] + part[1][row][col]
            + part[2][row][col] + part[3][row][col] + bias[n0 + col];
  C[(size_t)(m0 + row) * Cs_ + n0 + col] = sum;
}

// ---------------- launch ----------------
extern "C" void kernel_launch(void* const* d_in, const int* in_sizes, int n_in,
                              void* d_out, int out_size, void* d_ws, size_t ws_size,
                              hipStream_t stream) {
  const float* s      = (const float*)d_in[0];
  const float* z      = (const float*)d_in[1];
  const float* rot    = (const float*)d_in[2];
  const float* trans  = (const float*)d_in[3];
  const float* mask   = (const float*)d_in[4];
  const int*   E      = (const int*)  d_in[5];
  const float* W_q    = (const float*)d_in[6];
  const float* b_q    = (const float*)d_in[7];
  const float* W_kv   = (const float*)d_in[8];
  const float* b_kv   = (const float*)d_in[9];
  const float* W_qp   = (const float*)d_in[10];
  const float* b_qp   = (const float*)d_in[11];
  const float* W_kvp  = (const float*)d_in[12];
  const float* b_kvp  = (const float*)d_in[13];
  const float* W_b    = (const float*)d_in[14];
  const float* b_b    = (const float*)d_in[15];  (void)b_b; // row-constant in softmax -> dropped
  const float* head_w = (const float*)d_in[16];
  const float* W_out  = (const float*)d_in[17];
  const float* b_out  = (const float*)d_in[18];

  // Workspace layout (float-slot offsets). Staging region [0..1254528) is
  // consumed by prep_kernel; catb/WoutT alias it afterwards (order enforced
  // by launch sequence on `stream`). Total footprint: 2424960 fs = 9.7 MB.
  float* ws = (float*)d_ws;
  short* WallT   = (short*)(ws + 0);        // 442368 sh = 221184 fs   [staging]
  float* ball    = ws + 221184;             // 1152                    [staging]
  short* sb      = (short*)(ws + 222336);   // 294912 sh = 147456 fs   [staging]
  float* proj    = ws + 369792;             // 884736                  [staging]
  short* catb    = (short*)(ws + 0);        // 1622016 sh = 811008 fs  [aliases staging head]
  short* WoutT   = (short*)(ws + 811008);   // 811008 sh = 405504 fs   [aliases proj tail]
  short* Amat    = (short*)(ws + 1254528);  // 589824 sh = 294912 fs
  short* Bmat    = (short*)(ws + 1549440);  // 294912 fs
  short* VmatT   = (short*)(ws + 1844352);  // 294912 fs
  float* colbias = ws + 2139264;            // 9216
  float* bias_e  = ws + 2148480;            // 276480 -> end 2424960 fs

  pack_kernel<<<(Cs_ * PROJN + PROJN + L_ * Cs_ + 255) / 256, 256, 0, stream>>>(
      W_q, b_q, W_kv, b_kv, W_qp, b_qp, W_kvp, b_kvp, s, WallT, ball, sb);

  proj_mfma<<<dim3(L_ / 16, PROJN / 16), 64, 0, stream>>>(sb, WallT, ball, proj);

  prep_kernel<<<36, 256, 0, stream>>>(proj, rot, trans, mask, head_w, Amat, Bmat, VmatT, colbias);

  // cvt_wout AFTER prep_kernel: WoutT aliases the proj region.
  cvt_wout<<<dim3(CONCAT_ / 32, Cs_ / 32), 256, 0, stream>>>(W_out, WoutT);

  bias_mfma<<<(L_ * NB_) / 16, 64, 0, stream>>>(z, W_b, bias_e);

  attn_mfma<<<dim3(L_ / 16, H_), 256, 0, stream>>>(
      Amat, Bmat, VmatT, colbias, bias_e, E, rot, trans, z, catb);

  gemm_out_mfma<<<dim3(L_ / 16, Cs_ / 16), 256, 0, stream>>>(catb, WoutT, b_out, (float*)d_out);
}

// Round 10
// 167.832 us; speedup vs baseline: 3.5270x; 1.1155x over previous
//
#include <hip/hip_runtime.h>
#include <hip/hip_bf16.h>
#include <math.h>

// Problem constants
#define L_    768
#define Cs_   384
#define Cz_   128
#define H_    12
#define NB_   30
#define CONCAT_ 2112
#define PROJN 1152   // 192 q + 384 kv + 144 qp + 432 kvp

#define SCALE_QK  0.14433756729740643f   // sqrt(1/48)
#define SQRT3INV  0.5773502691896258f    // sqrt(1/3)
#define WC_       0.13608276348795434f   // sqrt(1/54)
#define INF_      100000.0f

typedef short bf16x8 __attribute__((ext_vector_type(8)));
typedef float f32x4 __attribute__((ext_vector_type(4)));

__device__ __forceinline__ short f2b(float f) {
  __hip_bfloat16 b = __float2bfloat16(f);
  return *reinterpret_cast<short*>(&b);
}
__device__ __forceinline__ float b2f(short s) {
  __hip_bfloat16 b;
  *reinterpret_cast<short*>(&b) = s;
  return __bfloat162float(b);
}

// ---------------- K1: preprocess (pack weights, s->bf16, WbT, WoutT) ----------------
#define PK_E1 (Cs_*PROJN)          // 442368  WallT
#define PK_E2 (PK_E1 + PROJN)      // 443520  ball
#define PK_E3 (PK_E2 + L_*Cs_)     // 738432  sb
#define PK_E4 (PK_E3 + H_*Cz_)     // 739968  WbT
#define PK_BLOCKS ((PK_E4 + 255) / 256)   // 2891
__global__ __launch_bounds__(256) void preprocess(
    const float* __restrict__ Wq, const float* __restrict__ bq,
    const float* __restrict__ Wkv, const float* __restrict__ bkv,
    const float* __restrict__ Wqp, const float* __restrict__ bqp,
    const float* __restrict__ Wkvp, const float* __restrict__ bkvp,
    const float* __restrict__ s, const float* __restrict__ Wb,
    const float* __restrict__ Wout,
    short* __restrict__ WallT, float* __restrict__ ball,
    short* __restrict__ sb, short* __restrict__ WbT,
    short* __restrict__ WoutT) {
  __shared__ float tile[32][33];
  const int bid = blockIdx.x;
  if (bid < PK_BLOCKS) {
    int e = bid * 256 + threadIdx.x;
    if (e < PK_E1) {                       // WallT [1152][384] bf16
      int col = e / 384, kk = e % 384;
      float v;
      if (col < 192)      v = Wq[kk*192 + col];
      else if (col < 576) v = Wkv[kk*384 + (col-192)];
      else if (col < 720) v = Wqp[kk*144 + (col-576)];
      else                v = Wkvp[kk*432 + (col-720)];
      WallT[e] = f2b(v);
    } else if (e < PK_E2) {                // ball
      int col = e - PK_E1;
      float v;
      if (col < 192)      v = bq[col];
      else if (col < 576) v = bkv[col-192];
      else if (col < 720) v = bqp[col-576];
      else                v = bkvp[col-720];
      ball[col] = v;
    } else if (e < PK_E3) {                // s -> bf16
      int x = e - PK_E2;
      sb[x] = f2b(s[x]);
    } else if (e < PK_E4) {                // WbT [12][128] bf16 (n-major)
      int x = e - PK_E3;
      WbT[x] = f2b(Wb[(x & 127) * H_ + (x >> 7)]);
    }
  } else {                                 // W_out -> bf16 transposed [384][2112]
    const int b2 = bid - PK_BLOCKS;
    const int k0 = (b2 % 66) * 32, n0 = (b2 / 66) * 32;
    const int tn = threadIdx.x & 31, tk = threadIdx.x >> 5;
    #pragma unroll
    for (int kk = tk; kk < 32; kk += 8)
      tile[kk][tn] = Wout[(size_t)(k0 + kk) * Cs_ + n0 + tn];
    __syncthreads();
    #pragma unroll
    for (int rr = tk; rr < 32; rr += 8)
      WoutT[(size_t)(n0 + rr) * CONCAT_ + k0 + tn] = f2b(tile[tn][rr]);
  }
}

// ---------------- K2: proj GEMM (transposed out) + edge-bias GEMM, merged ----------------
// bid < 3456: projT[n][m] = (s @ Wall + ball)^T   (f32, [1152][768])
// else      : bias_e[m][h] = sqrt(1/3) * z[m,:] @ Wb[:,h]   (m = i*30+k)
__global__ __launch_bounds__(64) void proj_bias_mfma(
    const short* __restrict__ A,    // [768][384] bf16
    const short* __restrict__ Bt,   // [1152][384] bf16
    const float* __restrict__ bias, // [1152]
    float* __restrict__ CT,         // [1152][768]
    const float* __restrict__ z,    // [23040][128]
    const short* __restrict__ WbT,  // [12][128] bf16
    float* __restrict__ bias_e) {   // [23040][12]
  const int l = threadIdx.x, r = l & 15, kg = l >> 4;
  const int bid = blockIdx.x;
  if (bid < 3456) {
    const int m0 = (bid % 48) * 16, n0 = (bid / 48) * 16;
    const short* ap = A  + (size_t)(m0 + r) * 384 + kg * 8;
    const short* bp = Bt + (size_t)(n0 + r) * 384 + kg * 8;
    f32x4 acc = {0.f, 0.f, 0.f, 0.f};
    #pragma unroll
    for (int k = 0; k < 12; ++k) {
      bf16x8 af = *(const bf16x8*)(ap + k * 32);
      bf16x8 bfv = *(const bf16x8*)(bp + k * 32);
      acc = __builtin_amdgcn_mfma_f32_16x16x32_bf16(af, bfv, acc, 0, 0, 0);
    }
    const float bv = bias[n0 + r];
    float4 st;
    st.x = acc[0] + bv; st.y = acc[1] + bv; st.z = acc[2] + bv; st.w = acc[3] + bv;
    *(float4*)&CT[(size_t)(n0 + r) * L_ + m0 + kg * 4] = st;
  } else {
    const int m0 = (bid - 3456) * 16;
    f32x4 acc = {0.f, 0.f, 0.f, 0.f};
    const float* zr = z + (size_t)(m0 + r) * Cz_ + kg * 8;
    #pragma unroll
    for (int kc = 0; kc < 4; ++kc) {
      float4 a0 = *(const float4*)(zr + kc * 32);
      float4 a1 = *(const float4*)(zr + kc * 32 + 4);
      bf16x8 af, bfv;
      af[0]=f2b(a0.x); af[1]=f2b(a0.y); af[2]=f2b(a0.z); af[3]=f2b(a0.w);
      af[4]=f2b(a1.x); af[5]=f2b(a1.y); af[6]=f2b(a1.z); af[7]=f2b(a1.w);
      if (r < H_) {
        bfv = *(const bf16x8*)(WbT + r * Cz_ + kc * 32 + kg * 8);
      } else {
        #pragma unroll
        for (int j = 0; j < 8; ++j) bfv[j] = 0;
      }
      acc = __builtin_amdgcn_mfma_f32_16x16x32_bf16(af, bfv, acc, 0, 0, 0);
    }
    if (r < H_) {
      #pragma unroll
      for (int j = 0; j < 4; ++j)
        bias_e[(size_t)(m0 + kg * 4 + j) * H_ + r] = SQRT3INV * acc[j];
    }
  }
}

// ---------------- K3: prep Amat/Bmat/VmatT/colbias (coalesced reads from projT) ----------------
__global__ __launch_bounds__(128) void prep_kernel(const float* __restrict__ pT,   // [1152][768]
                                                   const float* __restrict__ rot,
                                                   const float* __restrict__ trans,
                                                   const float* __restrict__ maskp,
                                                   const float* __restrict__ head_w,
                                                   short* __restrict__ Amat,
                                                   short* __restrict__ Bmat,
                                                   short* __restrict__ VmatT,
                                                   float* __restrict__ colbias) {
  const int h = blockIdx.x / 6;
  const int i = (blockIdx.x % 6) * 128 + threadIdx.x;
  #define PT(c) pT[(size_t)(c) * L_ + i]
  const float* R = rot + i * 9;
  const float* T = trans + i * 3;
  const float c2 = log1pf(expf(head_w[h])) * WC_;
  short* arow = Amat + ((size_t)h * L_ + i) * 64;
  short* brow = Bmat + ((size_t)h * L_ + i) * 64;
  #pragma unroll
  for (int c = 0; c < 16; ++c) {
    arow[c] = f2b(PT(h * 16 + c) * SCALE_QK);
    brow[c] = f2b(PT(192 + h * 32 + c));
    VmatT[((size_t)h * 64 + c) * L_ + i] = f2b(PT(192 + h * 32 + 16 + c));
  }
  // q points (4): x = c2 * global
  #pragma unroll
  for (int pt = 0; pt < 4; ++pt) {
    int idx = h * 4 + pt;
    float lx = PT(576 + idx), ly = PT(576 + 48 + idx), lz = PT(576 + 96 + idx);
    float g[3];
    g[0] = R[0]*lx + R[1]*ly + R[2]*lz + T[0];
    g[1] = R[3]*lx + R[4]*ly + R[5]*lz + T[1];
    g[2] = R[6]*lx + R[7]*ly + R[8]*lz + T[2];
    #pragma unroll
    for (int d = 0; d < 3; ++d) {
      float x = c2 * g[d];
      short xh = f2b(x);
      short xl = f2b(x - b2f(xh));
      arow[16 + pt*3 + d] = xh; arow[28 + pt*3 + d] = xh;
      arow[40 + pt*3 + d] = xl; arow[52 + pt*3 + d] = xl;
    }
  }
  // k points (4): raw hi/lo + |kp|^2
  float s2 = 0.f;
  #pragma unroll
  for (int pt = 0; pt < 4; ++pt) {
    int idx = h * 12 + pt;
    float lx = PT(720 + idx), ly = PT(720 + 144 + idx), lz = PT(720 + 288 + idx);
    float g[3];
    g[0] = R[0]*lx + R[1]*ly + R[2]*lz + T[0];
    g[1] = R[3]*lx + R[4]*ly + R[5]*lz + T[1];
    g[2] = R[6]*lx + R[7]*ly + R[8]*lz + T[2];
    #pragma unroll
    for (int d = 0; d < 3; ++d) {
      s2 += g[d] * g[d];
      short kh = f2b(g[d]);
      short kl = f2b(g[d] - b2f(kh));
      brow[16 + pt*3 + d] = kh; brow[28 + pt*3 + d] = kl;
      brow[40 + pt*3 + d] = kh; brow[52 + pt*3 + d] = kl;
    }
  }
  colbias[h * L_ + i] = -0.5f * c2 * s2 + INF_ * (maskp[i] - 1.0f);
  // v points (8): hi/lo
  #pragma unroll
  for (int pt = 4; pt < 12; ++pt) {
    int idx = h * 12 + pt;
    float lx = PT(720 + idx), ly = PT(720 + 144 + idx), lz = PT(720 + 288 + idx);
    float g[3];
    g[0] = R[0]*lx + R[1]*ly + R[2]*lz + T[0];
    g[1] = R[3]*lx + R[4]*ly + R[5]*lz + T[1];
    g[2] = R[6]*lx + R[7]*ly + R[8]*lz + T[2];
    #pragma unroll
    for (int d = 0; d < 3; ++d) {
      int pc = (pt - 4) * 3 + d;
      short vh = f2b(g[d]);
      short vl = f2b(g[d] - b2f(vh));
      VmatT[((size_t)h * 64 + 16 + pc) * L_ + i] = vh;
      VmatT[((size_t)h * 64 + 40 + pc) * L_ + i] = vl;
    }
  }
  #undef PT
}

// ---------------- K4: fused MFMA attention ----------------
// block = (head, 16-row tile), 4 waves of 64. LDS ~49.3KB -> target 3 blocks/CU.
#define SLS 772   // Sl row stride in f32 (16B aligned)
__global__ __launch_bounds__(256, 3) void attn_mfma(
    const short* __restrict__ Amat,    // [12][768][64]
    const short* __restrict__ Bmat,    // [12][768][64]
    const short* __restrict__ VmatT,   // [12][64][768]
    const float* __restrict__ colbias, // [12][768]
    const float* __restrict__ bias_e,  // [768*30][12]
    const int*   __restrict__ E_idx,   // [768][30]
    const float* __restrict__ rot,     // [768][9]
    const float* __restrict__ trans,   // [768][3]
    const float* __restrict__ z,       // [768][30][128]
    short* __restrict__ catb)          // [768][2112] bf16
{
  const int h = blockIdx.y;
  const int i0 = blockIdx.x * 16;
  const int t = threadIdx.x;
  const int lane = t & 63, wave = t >> 6;
  const int fr = lane & 15, kg = lane >> 4;

  __shared__ __align__(16) float Sl[16][SLS];  // logits -> P bf16 (words 0..383); words 512..559 = ptb
  __shared__ unsigned short eidx[16][NB_];
  __shared__ float denom[16];
  #define PTB(r, c) Sl[r][512 + (c)]

  // A fragments for this row-tile
  const short* Ab = Amat + ((size_t)h * L_ + i0 + fr) * 64 + kg * 8;
  bf16x8 a0 = *(const bf16x8*)(Ab);
  bf16x8 a1 = *(const bf16x8*)(Ab + 32);

  for (int e = t; e < 16 * NB_; e += 256)
    eidx[e / NB_][e % NB_] = (unsigned short)E_idx[(i0 + e / NB_) * NB_ + e % NB_];

  // ---- pass 1: logits. wave w covers j in [w*192, w*192+192) ----
  #pragma unroll 3
  for (int tt = 0; tt < 12; ++tt) {
    const int j0 = wave * 192 + tt * 16;
    const short* Bb = Bmat + ((size_t)h * L_ + j0 + fr) * 64 + kg * 8;
    f32x4 acc = {0.f, 0.f, 0.f, 0.f};
    acc = __builtin_amdgcn_mfma_f32_16x16x32_bf16(a0, *(const bf16x8*)(Bb), acc, 0, 0, 0);
    acc = __builtin_amdgcn_mfma_f32_16x16x32_bf16(a1, *(const bf16x8*)(Bb + 32), acc, 0, 0, 0);
    const float cb = colbias[h * L_ + j0 + fr];
    #pragma unroll
    for (int j = 0; j < 4; ++j)
      Sl[kg * 4 + j][j0 + fr] = acc[j] + cb;
  }
  __syncthreads();

  // ---- edge bias scatter (480 elements: grid-stride) ----
  for (int e = t; e < 16 * NB_; e += 256) {
    int r = e / NB_, k = e % NB_;
    Sl[r][eidx[r][k]] += bias_e[(size_t)((i0 + r) * NB_ + k) * H_ + h];
  }
  __syncthreads();

  // ---- fused softmax + f32->bf16 pack. 16 threads/row; thread sub owns cols [sub*48, sub*48+48).
  // All 16 threads of a row are in the same wave: reads (reg staging) precede the packed writes
  // in program order, so overwriting the row in-place is lockstep-safe.
  {
    const int r = t >> 4, sub = t & 15;
    float4 v[12];
    const float4* src = (const float4*)&Sl[r][sub * 48];
    #pragma unroll
    for (int n = 0; n < 12; ++n) v[n] = src[n];
    float mx = -1e30f;
    #pragma unroll
    for (int n = 0; n < 12; ++n)
      mx = fmaxf(mx, fmaxf(fmaxf(v[n].x, v[n].y), fmaxf(v[n].z, v[n].w)));
    #pragma unroll
    for (int d = 8; d; d >>= 1) mx = fmaxf(mx, __shfl_xor(mx, d, 16));
    float sum = 0.f;
    unsigned* dst = (unsigned*)&Sl[r][0] + sub * 24;
    #pragma unroll
    for (int n = 0; n < 12; ++n) {
      float e0 = __expf(v[n].x - mx), e1 = __expf(v[n].y - mx);
      float e2 = __expf(v[n].z - mx), e3 = __expf(v[n].w - mx);
      sum += (e0 + e1) + (e2 + e3);
      dst[2*n]   = (unsigned)(unsigned short)f2b(e0) | ((unsigned)(unsigned short)f2b(e1) << 16);
      dst[2*n+1] = (unsigned)(unsigned short)f2b(e2) | ((unsigned)(unsigned short)f2b(e3) << 16);
    }
    #pragma unroll
    for (int d = 8; d; d >>= 1) sum += __shfl_xor(sum, d, 16);
    if (sub == 0) denom[r] = sum;
  }
  __syncthreads();

  // ---- pass 2: PV. wave = channel tile (16 ch of [v16|vph24|vpl24]) ----
  f32x4 oacc = {0.f, 0.f, 0.f, 0.f};
  const short* Vb = VmatT + ((size_t)h * 64 + wave * 16 + fr) * L_ + kg * 8;
  const short* PbRow = (const short*)&Sl[fr][0];
  #pragma unroll 4
  for (int ks = 0; ks < 24; ++ks) {
    bf16x8 pa = *(const bf16x8*)(PbRow + ks * 32 + kg * 8);
    bf16x8 vb = *(const bf16x8*)(Vb + ks * 32);
    oacc = __builtin_amdgcn_mfma_f32_16x16x32_bf16(pa, vb, oacc, 0, 0, 0);
  }
  if (wave == 0) {
    #pragma unroll
    for (int j = 0; j < 4; ++j) {
      int r = kg * 4 + j;
      catb[(size_t)(i0 + r) * CONCAT_ + h * 16 + fr] = f2b(oacc[j] / denom[r]);
    }
  } else {
    int ch = wave * 16 + fr;
    int dest = (ch < 40) ? (ch - 16) : (24 + ch - 40);
    #pragma unroll
    for (int j = 0; j < 4; ++j)
      PTB(kg * 4 + j, dest) = oacc[j];
  }
  __syncthreads();

  // ---- rotate o_pt back, norms ----
  if (t < 128) {
    int r = t >> 3, pt = t & 7;
    int ii = i0 + r;
    float di = 1.0f / denom[r];
    const float* T = trans + ii * 3;
    float gx = (PTB(r, pt * 3 + 0) + PTB(r, 24 + pt * 3 + 0)) * di - T[0];
    float gy = (PTB(r, pt * 3 + 1) + PTB(r, 24 + pt * 3 + 1)) * di - T[1];
    float gz = (PTB(r, pt * 3 + 2) + PTB(r, 24 + pt * 3 + 2)) * di - T[2];
    const float* R = rot + ii * 9;
    float lx = R[0] * gx + R[3] * gy + R[6] * gz;
    float ly = R[1] * gx + R[4] * gy + R[7] * gz;
    float lz = R[2] * gx + R[5] * gy + R[8] * gz;
    float nrm = sqrtf(lx * lx + ly * ly + lz * lz + 1e-8f);
    short* crow = catb + (size_t)ii * CONCAT_;
    crow[192 + h * 8 + pt] = f2b(lx);
    crow[288 + h * 8 + pt] = f2b(ly);
    crow[384 + h * 8 + pt] = f2b(lz);
    crow[480 + h * 8 + pt] = f2b(nrm);
  }

  // ---- sparse o_pair: weights read from bf16 P at eidx ----
  {
    const int r = t >> 4, sub = t & 15;
    const int ii = i0 + r;
    const float di = 1.0f / denom[r];
    const unsigned* Pw = (const unsigned*)&Sl[r][0];
    float accs[8];
    #pragma unroll
    for (int n = 0; n < 8; ++n) accs[n] = 0.f;
    #pragma unroll 5
    for (int k = 0; k < NB_; ++k) {
      int j = eidx[r][k];
      unsigned pw = Pw[j >> 1];
      float w = b2f((short)((j & 1) ? (pw >> 16) : (pw & 0xffff)));
      const float* zp = z + ((size_t)ii * NB_ + k) * Cz_ + sub;
      #pragma unroll
      for (int n = 0; n < 8; ++n) accs[n] += w * zp[n * 16];
    }
    short* crow = catb + (size_t)ii * CONCAT_ + 576 + h * Cz_;
    #pragma unroll
    for (int n = 0; n < 8; ++n) crow[sub + n * 16] = f2b(accs[n] * di);
  }
  #undef PTB
}

// ---------------- K5: bf16 MFMA out-GEMM, 4-wave k-split ----------------
__global__ __launch_bounds__(256) void gemm_out_mfma(const short* __restrict__ A,   // [768][2112]
                                                     const short* __restrict__ Bt,  // [384][2112]
                                                     const float* __restrict__ bias,
                                                     float* __restrict__ C) {
  const int t = threadIdx.x;
  const int w = t >> 6, l = t & 63;
  const int r = l & 15, kg = l >> 4;
  const int m0 = blockIdx.x * 16, n0 = blockIdx.y * 16;
  __shared__ float part[4][16][17];
  const int kcnt = (w < 2) ? 17 : 16;                 // 66 = 17+17+16+16 K-chunks of 32
  const int koff = (w < 2) ? w * 17 : 34 + (w - 2) * 16;
  const short* ap = A  + (size_t)(m0 + r) * CONCAT_ + koff * 32 + kg * 8;
  const short* bp = Bt + (size_t)(n0 + r) * CONCAT_ + koff * 32 + kg * 8;
  f32x4 acc = {0.f, 0.f, 0.f, 0.f};
  #pragma unroll 4
  for (int k = 0; k < kcnt; ++k) {
    bf16x8 af = *(const bf16x8*)(ap + k * 32);
    bf16x8 bfv = *(const bf16x8*)(bp + k * 32);
    acc = __builtin_amdgcn_mfma_f32_16x16x32_bf16(af, bfv, acc, 0, 0, 0);
  }
  #pragma unroll
  for (int j = 0; j < 4; ++j) part[w][kg * 4 + j][r] = acc[j];
  __syncthreads();
  const int row = t >> 4, col = t & 15;
  float sum = part[0][row][col] + part[1][row][col]
            + part[2][row][col] + part[3][row][col] + bias[n0 + col];
  C[(size_t)(m0 + row) * Cs_ + n0 + col] = sum;
}

// ---------------- launch ----------------
extern "C" void kernel_launch(void* const* d_in, const int* in_sizes, int n_in,
                              void* d_out, int out_size, void* d_ws, size_t ws_size,
                              hipStream_t stream) {
  const float* s      = (const float*)d_in[0];
  const float* z      = (const float*)d_in[1];
  const float* rot    = (const float*)d_in[2];
  const float* trans  = (const float*)d_in[3];
  const float* mask   = (const float*)d_in[4];
  const int*   E      = (const int*)  d_in[5];
  const float* W_q    = (const float*)d_in[6];
  const float* b_q    = (const float*)d_in[7];
  const float* W_kv   = (const float*)d_in[8];
  const float* b_kv   = (const float*)d_in[9];
  const float* W_qp   = (const float*)d_in[10];
  const float* b_qp   = (const float*)d_in[11];
  const float* W_kvp  = (const float*)d_in[12];
  const float* b_kvp  = (const float*)d_in[13];
  const float* W_b    = (const float*)d_in[14];
  const float* b_b    = (const float*)d_in[15];  (void)b_b; // row-constant in softmax -> dropped
  const float* head_w = (const float*)d_in[16];
  const float* W_out  = (const float*)d_in[17];
  const float* b_out  = (const float*)d_in[18];

  // Workspace (float-slot offsets). Staging [0..1254528) consumed by prep;
  // catb aliases it afterwards. WoutT/WbT are NON-aliased (written first by
  // preprocess). Total 2831232 fs = 11.3 MB (13.05 MB proven safe).
  float* ws = (float*)d_ws;
  short* WallT   = (short*)(ws + 0);        // [staging]
  float* ball    = ws + 221184;             // [staging]
  short* sb      = (short*)(ws + 222336);   // [staging]
  float* projT   = ws + 369792;             // [1152][768] f32 [staging]
  short* catb    = (short*)(ws + 0);        // [768][2112] bf16, aliases staging head
  short* Amat    = (short*)(ws + 1254528);
  short* Bmat    = (short*)(ws + 1549440);
  short* VmatT   = (short*)(ws + 1844352);
  float* colbias = ws + 2139264;
  float* bias_e  = ws + 2148480;            // -> 2424960
  short* WoutT   = (short*)(ws + 2424960);  // [384][2112] bf16 -> 2830464
  short* WbT     = (short*)(ws + 2830464);  // [12][128] bf16  -> 2831232

  preprocess<<<PK_BLOCKS + 792, 256, 0, stream>>>(
      W_q, b_q, W_kv, b_kv, W_qp, b_qp, W_kvp, b_kvp, s, W_b, W_out,
      WallT, ball, sb, WbT, WoutT);

  proj_bias_mfma<<<3456 + 1440, 64, 0, stream>>>(
      sb, WallT, ball, projT, z, WbT, bias_e);

  prep_kernel<<<72, 128, 0, stream>>>(projT, rot, trans, mask, head_w,
                                      Amat, Bmat, VmatT, colbias);

  attn_mfma<<<dim3(L_ / 16, H_), 256, 0, stream>>>(
      Amat, Bmat, VmatT, colbias, bias_e, E, rot, trans, z, catb);

  gemm_out_mfma<<<dim3(L_ / 16, Cs_ / 16), 256, 0, stream>>>(catb, WoutT, b_out, (float*)d_out);
}